// Round 7
// baseline (3191.469 us; speedup 1.0000x reference)
//
#include <hip/hip_runtime.h>

typedef unsigned short u16;
typedef unsigned int u32;
typedef __attribute__((ext_vector_type(8))) short bf16x8;
typedef __attribute__((ext_vector_type(4))) float f32x4;

__device__ __forceinline__ float b2f(u16 h) {
  union { float f; unsigned u; } v; v.u = ((unsigned)h) << 16; return v.f;
}
__device__ __forceinline__ u16 f2b(float f) {
  union { float f; unsigned u; } v; v.f = f;
  unsigned r = v.u + 0x7fffu + ((v.u >> 16) & 1u);
  return (u16)(r >> 16);
}
__device__ __forceinline__ float hsig(float z) {
  return fminf(fmaxf(z * 0.16666667f + 0.5f, 0.f), 1.f);
}
// dtype-adaptive scalar load: flag=1 -> bf16, flag=0 -> fp32
__device__ __forceinline__ float ldf(const void* p, int i, int flag) {
  return flag ? b2f(((const u16*)p)[i]) : ((const float*)p)[i];
}
// bf16-rounded weight load (matches repack path exactly)
__device__ __forceinline__ float ldw(const void* p, int i, int flag) {
  return b2f(f2b(ldf(p, i, flag)));
}

__global__ void detect_dtype(const void* x, int* dflag) {
  __shared__ int cnt;
  if (threadIdx.x == 0) cnt = 0;
  __syncthreads();
  const u32* w = (const u32*)x;
  int c = 0;
  for (int i = threadIdx.x; i < 512; i += 256) {
    u32 e = (w[i] >> 7) & 0xFFu;
    if (e >= 100 && e < 130) c++;
  }
  atomicAdd(&cnt, c);
  __syncthreads();
  if (threadIdx.x == 0) *dflag = (cnt >= 256) ? 1 : 0;
}

// canonicalize x to hi/lo bf16 planes (lo = residual; 0 if input already bf16)
__global__ void canon_x(const void* src, u16* dst, const int* dflag, int n) {
  int i = blockIdx.x * 256 + threadIdx.x;
  if (i >= n) return;
  int fl = *dflag;
  float v = ldf(src, i, fl);
  u16 hi = f2b(v);
  dst[i] = hi;
  dst[i + n] = f2b(v - b2f(hi));
}

// ---------------------------------------------------------------------------
// Fused ConvLSTM step (implicit GEMM, MFMA 16x16x32 bf16) + LSTM update +
// (MODE 0/1) BN + 2x2 maxpool or (MODE 2) GAP accumulation.
// Activations are hi/lo bf16 pairs (plane strides sPL/hPL/pPL); the K-loop
// runs 2 passes (hi, lo) restaging the same LDS buffers; acc persists.
// ---------------------------------------------------------------------------
template<int KS, int MODE, int H, int W>
__global__ __launch_bounds__(256, 2)
void lstm_step(const u16* __restrict__ src, int aBStride, size_t sPL,
               const u16* __restrict__ wA, const u16* __restrict__ wU,
               const u16* __restrict__ hin, size_t hPL, u16* __restrict__ hout,
               float* __restrict__ cbuf, const void* __restrict__ bias,
               const void* __restrict__ bng, const void* __restrict__ bnb,
               const void* __restrict__ bnm, const void* __restrict__ bnv,
               u16* __restrict__ pooled, size_t pPL, float* __restrict__ gap,
               const int* __restrict__ dflag)
{
  constexpr int PAD = KS / 2;
  constexpr int TW = 8 + 2 * PAD;
  constexpr int TH = 16 + 2 * PAD;
  constexpr int KK = KS * KS;
  constexpr int KT = (MODE == 0) ? (KK + 1) : (2 * KK);
  constexpr int SSTR = 40;

  __shared__ __align__(16) u16 sH[TH * TW * SSTR];
  __shared__ __align__(16) u16 sA[(MODE == 0) ? (TH * TW) : (TH * TW * SSTR)];
  __shared__ __align__(16) u16 wbuf[2][4096];
  __shared__ float sgap[32];

  const int tid = threadIdx.x;
  const int b = blockIdx.y;
  constexpr int TXT = W / 8;
  const int bx0 = (blockIdx.x % TXT) * 8;
  const int gy0 = (blockIdx.x / TXT) * 16;

  const int w = tid >> 6, lane = tid & 63;
  const int j = w & 1, R0 = (w >> 1) * 8;
  const int q = lane >> 4, col = lane & 15;
  const int my = (lane >> 3) & 1, mx = lane & 7;

  if (tid < 32) sgap[tid] = 0.f;

  auto stageH = [&](int pl) {
    const u16* hsrc = hin + (size_t)pl * hPL;
    for (int i = tid; i < TH * TW * 4; i += 256) {
      int p = i >> 2, ch = i & 3;
      int sy = p / TW, sx = p - sy * TW;
      int gy = gy0 + sy - PAD, gx = bx0 + sx - PAD;
      int4 v; v.x = v.y = v.z = v.w = 0;
      if (gy >= 0 && gy < H && gx >= 0 && gx < W)
        v = *(const int4*)(hsrc + (((size_t)(b * H + gy) * W + gx) << 5) + ch * 8);
      *(int4*)(&sH[p * SSTR + ch * 8]) = v;
    }
  };
  auto stageS = [&](int pl) {
    const u16* asrc = src + (size_t)pl * sPL;
    if (MODE == 0) {
      for (int i = tid; i < TH * TW; i += 256) {
        int sy = i / TW, sx = i - sy * TW;
        int gy = gy0 + sy - PAD, gx = bx0 + sx - PAD;
        u16 v = 0;
        if (gy >= 0 && gy < H && gx >= 0 && gx < W)
          v = asrc[(size_t)b * aBStride + gy * W + gx];
        sA[i] = v;
      }
    } else {
      for (int i = tid; i < TH * TW * 4; i += 256) {
        int p = i >> 2, ch = i & 3;
        int sy = p / TW, sx = p - sy * TW;
        int gy = gy0 + sy - PAD, gx = bx0 + sx - PAD;
        int4 v; v.x = v.y = v.z = v.w = 0;
        if (gy >= 0 && gy < H && gx >= 0 && gx < W)
          v = *(const int4*)(asrc + (size_t)b * aBStride + (((size_t)gy * W + gx) << 5) + ch * 8);
        *(int4*)(&sA[p * SSTR + ch * 8]) = v;
      }
    }
  };

  auto wsel = [&](int kt) -> const u16* {
    if (MODE == 0) return (kt == 0) ? wA : (wU + (kt - 1) * 4096);
    return (kt < KK) ? (wA + kt * 4096) : (wU + (kt - KK) * 4096);
  };
  {
    const u16* wsrc = wsel(0);
    int4 a0 = *(const int4*)(wsrc + tid * 16);
    int4 a1 = *(const int4*)(wsrc + tid * 16 + 8);
    *(int4*)(&wbuf[0][tid * 16]) = a0;
    *(int4*)(&wbuf[0][tid * 16 + 8]) = a1;
  }
  stageH(0); stageS(0);
  __syncthreads();

  f32x4 acc[4][4] = {};
  int abase[4];
#pragma unroll
  for (int mt = 0; mt < 4; mt++)
    abase[mt] = ((R0 + 2 * mt + my) * TW + mx) * SSTR + q * 8;

  constexpr int KT2 = 2 * KT;
  for (int i = 0; i < KT2; ++i) {
    if (i == KT) {            // pass boundary: restage lo planes
      stageH(1); stageS(1);
      __syncthreads();
    }
    const int kt = (i < KT) ? i : i - KT;
    const bool pf = (i + 1) < KT2;
    const int nkt = ((i + 1) < KT) ? (i + 1) : (i + 1 - KT);
    int4 wn0, wn1;
    if (pf) {
      const u16* wsrc = wsel(nkt);
      wn0 = *(const int4*)(wsrc + tid * 16);
      wn1 = *(const int4*)(wsrc + tid * 16 + 8);
    }
    bf16x8 a[4];
    if (MODE == 0 && kt == 0) {
#pragma unroll
      for (int mt = 0; mt < 4; mt++) {
        union { bf16x8 v; u16 e[8]; } u;
#pragma unroll
        for (int jj = 0; jj < 8; jj++) {
          int k = q * 8 + jj;
          u16 val = 0;
          if (k < KK) {
            int kh = k / KS, kw = k - kh * KS;
            val = sA[(R0 + 2 * mt + my + kh) * TW + (mx + kw)];
          }
          u.e[jj] = val;
        }
        a[mt] = u.v;
      }
    } else {
      int tap; const u16* s;
      if (MODE == 0)      { tap = kt - 1;  s = sH; }
      else if (kt < KK)   { tap = kt;      s = sA; }
      else                { tap = kt - KK; s = sH; }
      const int kh = tap / KS, kw = tap - kh * KS;
      const int aoff = (kh * TW + kw) * SSTR;
#pragma unroll
      for (int mt = 0; mt < 4; mt++)
        a[mt] = *(const bf16x8*)(s + abase[mt] + aoff);
    }
    const u16* wb = wbuf[i & 1];
    bf16x8 bf[4];
#pragma unroll
    for (int g = 0; g < 4; g++)
      bf[g] = *(const bf16x8*)(wb + ((j + 2 * g) * 64 + lane) * 8);
#pragma unroll
    for (int mt = 0; mt < 4; mt++)
#pragma unroll
      for (int g = 0; g < 4; g++)
        acc[mt][g] = __builtin_amdgcn_mfma_f32_16x16x32_bf16(a[mt], bf[g], acc[mt][g], 0, 0, 0);
    if (pf) {
      *(int4*)(&wbuf[(i + 1) & 1][tid * 16]) = wn0;
      *(int4*)(&wbuf[(i + 1) & 1][tid * 16 + 8]) = wn1;
    }
    __syncthreads();
  }

  const int fl = *dflag;
  const int f = j * 16 + col;
  const float bi  = ldf(bias, f, fl);
  const float bff = ldf(bias, 32 + f, fl);
  const float bg  = ldf(bias, 64 + f, fl);
  const float bo  = ldf(bias, 96 + f, fl);
  float sc = 0.f, sh = 0.f;
  if (MODE < 2) {
    sc = ldf(bng, f, fl) * rsqrtf(ldf(bnv, f, fl) + 1e-3f);
    sh = ldf(bnb, f, fl) - ldf(bnm, f, fl) * sc;
  }
  const int oy = q >> 1;
  const int ox = (q & 1) * 4;
  float gsum = 0.f;
#pragma unroll
  for (int mt = 0; mt < 4; mt++) {
    const int y = gy0 + R0 + 2 * mt + oy;
    const size_t base = (((size_t)(b * H + y) * W + (bx0 + ox)) << 5) + f;
    float bnp[4];
#pragma unroll
    for (int r = 0; r < 4; r++) {
      float zi = acc[mt][0][r] + bi;
      float zf = acc[mt][1][r] + bff;
      float zg = acc[mt][2][r] + bg;
      float zo = acc[mt][3][r] + bo;
      float ig = hsig(zi), fg = hsig(zf), og = hsig(zo);
      float gg = fmaxf(zg, 0.f);
      size_t idx = base + ((size_t)r << 5);
      float cold = cbuf[idx];
      float cn = fg * cold + ig * gg;
      cbuf[idx] = cn;
      float hn = og * fmaxf(cn, 0.f);
      u16 hhi = f2b(hn);
      hout[idx] = hhi;
      hout[idx + hPL] = f2b(hn - b2f(hhi));
      if (MODE < 2) bnp[r] = hn * sc + sh; else gsum += hn;
    }
    if (MODE < 2) {
      float p0 = fmaxf(bnp[0], bnp[1]);
      float p1 = fmaxf(bnp[2], bnp[3]);
      p0 = fmaxf(p0, __shfl_xor(p0, 32));
      p1 = fmaxf(p1, __shfl_xor(p1, 32));
      if (q < 2) {
        const int py = (gy0 + R0 + 2 * mt) >> 1;
        const int px = (bx0 >> 1) + (q & 1) * 2;
        size_t pb = (((size_t)(b * (H / 2) + py) * (W / 2) + px) << 5) + f;
        u16 phi = f2b(p0);
        pooled[pb] = phi;
        pooled[pb + pPL] = f2b(p0 - b2f(phi));
        u16 qhi = f2b(p1);
        pooled[pb + 32] = qhi;
        pooled[pb + 32 + pPL] = f2b(p1 - b2f(qhi));
      }
    }
  }
  if (MODE == 2) {
    atomicAdd(&sgap[f], gsum);
    __syncthreads();
    if (tid < 32) atomicAdd(&gap[b * 32 + tid], sgap[tid]);
  }
}

__global__ void repack_w(const void* __restrict__ src, u16* __restrict__ dst,
                         int taps, const int* __restrict__ dflag) {
  int i = blockIdx.x * 256 + threadIdx.x;
  if (i >= taps * 512) return;
  int fl = *dflag;
  int l = i & 63, nt = (i >> 6) & 7, tap = i >> 9;
  int q = l >> 4, col = l & 15;
  u16 tmp[8];
#pragma unroll
  for (int j = 0; j < 8; j++)
    tmp[j] = f2b(ldf(src, (tap * 32 + q * 8 + j) * 128 + nt * 16 + col, fl));
#pragma unroll
  for (int j = 0; j < 8; j++) dst[i * 8 + j] = tmp[j];
}
__global__ void repack_x(const void* __restrict__ src, u16* __restrict__ dst,
                         const int* __restrict__ dflag) {
  int i = blockIdx.x * 256 + threadIdx.x;
  if (i >= 512) return;
  int fl = *dflag;
  int l = i & 63, nt = (i >> 6) & 7;
  int q = l >> 4, col = l & 15;
#pragma unroll
  for (int j = 0; j < 8; j++) {
    int k = q * 8 + j;
    dst[i * 8 + j] = (k < 25) ? f2b(ldf(src, k * 128 + nt * 16 + col, fl)) : (u16)0;
  }
}

__global__ void zero_ws(int4* p, int n) {
  int i = blockIdx.x * 256 + threadIdx.x;
  if (i < n) { int4 z; z.x = z.y = z.z = z.w = 0; p[i] = z; }
}
__global__ void fillv(float* out, int n, float v) {
  int i = blockIdx.x * 256 + threadIdx.x;
  if (i < n) out[i] = v;
}

// ======================= stage checks (scalar reference) ====================
// activation reads are hi+lo pairs; weights bf16-rounded (ldw)
__device__ __forceinline__ float pr(const u16* p, size_t i, size_t pl) {
  return b2f(p[i]) + b2f(p[i + pl]);
}

__global__ void chk1(const u16* xc, const void* k1, const void* b1,
                     const u16* h1b, const int* dflag, u32* stat) {
  int tid = threadIdx.x, fl = *dflag;
  int b = (tid & 3) * 5, y = (tid * 13) & 63, x = (tid * 29) & 63, f = (tid * 11) & 31;
  float z[4];
  for (int g = 0; g < 4; g++) z[g] = ldf(b1, g * 32 + f, fl);
  for (int kh = 0; kh < 5; kh++) { int yy = y + kh - 2; if (yy < 0 || yy >= 64) continue;
    for (int kw = 0; kw < 5; kw++) { int xx = x + kw - 2; if (xx < 0 || xx >= 64) continue;
      float xv = pr(xc, (size_t)b * 65536 + yy * 64 + xx, 1048576);
      for (int g = 0; g < 4; g++) z[g] += xv * ldw(k1, (kh * 5 + kw) * 128 + g * 32 + f, fl);
    } }
  float c = hsig(z[0]) * fmaxf(z[2], 0.f);
  float hs = hsig(z[3]) * fmaxf(c, 0.f);
  float hk = pr(h1b, (((size_t)b * 64 + y) * 64 + x) * 32 + f, 2097152);
  float d = fabsf(hs - hk) / (0.05f + fabsf(hs));
  atomicMax(&stat[0], __float_as_uint(d));
}

__global__ void chk2(const u16* h1b, const void* g1, const void* be1,
                     const void* m1, const void* v1, const u16* p1,
                     const int* dflag, u32* stat) {
  int tid = threadIdx.x, fl = *dflag;
  int b = (tid & 3) * 5, py = (tid * 13) & 31, px = (tid * 29) & 31, f = (tid * 11) & 31;
  float sc = ldf(g1, f, fl) * rsqrtf(ldf(v1, f, fl) + 1e-3f);
  float sh = ldf(be1, f, fl) - ldf(m1, f, fl) * sc;
  float m = -1e30f;
  for (int dy = 0; dy < 2; dy++)
    for (int dx = 0; dx < 2; dx++) {
      float h = pr(h1b, (((size_t)b * 64 + 2 * py + dy) * 64 + 2 * px + dx) * 32 + f, 2097152);
      m = fmaxf(m, h * sc + sh);
    }
  float pk = pr(p1, (((size_t)b * 32 + py) * 32 + px) * 32 + f, 524288);
  float d = fabsf(m - pk) / (0.05f + fabsf(m));
  atomicMax(&stat[1], __float_as_uint(d));
}

__global__ void chk3(const u16* p1, const void* k2, const void* b2,
                     const u16* h2b, const int* dflag, u32* stat) {
  int tid = threadIdx.x, fl = *dflag;
  int b = (tid & 3) * 5, y = (tid * 13) & 31, x = (tid * 29) & 31, f = (tid * 11) & 31;
  float z[4];
  for (int g = 0; g < 4; g++) z[g] = ldf(b2, g * 32 + f, fl);
  for (int kh = 0; kh < 5; kh++) { int yy = y + kh - 2; if (yy < 0 || yy >= 32) continue;
    for (int kw = 0; kw < 5; kw++) { int xx = x + kw - 2; if (xx < 0 || xx >= 32) continue;
      for (int c = 0; c < 32; c++) {
        float pv = pr(p1, (((size_t)b * 32 + yy) * 32 + xx) * 32 + c, 524288);
        z[0] += pv * ldw(k2, ((kh * 5 + kw) * 32 + c) * 128 + 0 + f, fl);
        z[1] += pv * ldw(k2, ((kh * 5 + kw) * 32 + c) * 128 + 32 + f, fl);
        z[2] += pv * ldw(k2, ((kh * 5 + kw) * 32 + c) * 128 + 64 + f, fl);
        z[3] += pv * ldw(k2, ((kh * 5 + kw) * 32 + c) * 128 + 96 + f, fl);
      } } }
  float c = hsig(z[0]) * fmaxf(z[2], 0.f);
  float hs = hsig(z[3]) * fmaxf(c, 0.f);
  float hk = pr(h2b, (((size_t)b * 32 + y) * 32 + x) * 32 + f, 524288);
  float d = fabsf(hs - hk) / (0.05f + fabsf(hs));
  atomicMax(&stat[2], __float_as_uint(d));
}

__global__ void chk4(const u16* p2, const void* k3, const void* b3,
                     const u16* hist, const int* dflag, u32* stat) {
  int tid = threadIdx.x, fl = *dflag;
  int b = (tid & 3) * 5, y = (tid * 13) & 15, x = (tid * 29) & 15, f = (tid * 11) & 31;
  float z[4];
  for (int g = 0; g < 4; g++) z[g] = ldf(b3, g * 32 + f, fl);
  for (int kh = 0; kh < 3; kh++) { int yy = y + kh - 1; if (yy < 0 || yy >= 16) continue;
    for (int kw = 0; kw < 3; kw++) { int xx = x + kw - 1; if (xx < 0 || xx >= 16) continue;
      for (int c = 0; c < 32; c++) {
        float pv = pr(p2, (((size_t)b * 16 + yy) * 16 + xx) * 32 + c, 131072);
        z[0] += pv * ldw(k3, ((kh * 3 + kw) * 32 + c) * 128 + 0 + f, fl);
        z[1] += pv * ldw(k3, ((kh * 3 + kw) * 32 + c) * 128 + 32 + f, fl);
        z[2] += pv * ldw(k3, ((kh * 3 + kw) * 32 + c) * 128 + 64 + f, fl);
        z[3] += pv * ldw(k3, ((kh * 3 + kw) * 32 + c) * 128 + 96 + f, fl);
      } } }
  float c = hsig(z[0]) * fmaxf(z[2], 0.f);
  float hs = hsig(z[3]) * fmaxf(c, 0.f);
  float hk = pr(hist, (((size_t)b * 16 + y) * 16 + x) * 32 + f, 131072);
  float d = fabsf(hs - hk) / (0.05f + fabsf(hs));
  atomicMax(&stat[3], __float_as_uint(d));
}

__global__ void chk5(const u16* xc, const void* k1, const void* u1, const void* b1,
                     const u16* h1b, const u16* h1a, const int* dflag, u32* stat) {
  int tid = threadIdx.x, fl = *dflag;
  int b = (tid & 3) * 5, y = (tid * 13) & 63, x = (tid * 29) & 63, f = (tid * 11) & 31;
  float z0[4], z1[4];
  for (int g = 0; g < 4; g++) { z0[g] = ldf(b1, g * 32 + f, fl); z1[g] = z0[g]; }
  for (int kh = 0; kh < 5; kh++) { int yy = y + kh - 2; if (yy < 0 || yy >= 64) continue;
    for (int kw = 0; kw < 5; kw++) { int xx = x + kw - 2; if (xx < 0 || xx >= 64) continue;
      float x0 = pr(xc, (size_t)b * 65536 + yy * 64 + xx, 1048576);
      float x1 = pr(xc, (size_t)b * 65536 + 4096 + yy * 64 + xx, 1048576);
      for (int g = 0; g < 4; g++) {
        float wv = ldw(k1, (kh * 5 + kw) * 128 + g * 32 + f, fl);
        z0[g] += x0 * wv; z1[g] += x1 * wv;
      }
      for (int c = 0; c < 32; c++) {
        float hv = pr(h1b, (((size_t)b * 64 + yy) * 64 + xx) * 32 + c, 2097152);
        z1[0] += hv * ldw(u1, ((kh * 5 + kw) * 32 + c) * 128 + 0 + f, fl);
        z1[1] += hv * ldw(u1, ((kh * 5 + kw) * 32 + c) * 128 + 32 + f, fl);
        z1[2] += hv * ldw(u1, ((kh * 5 + kw) * 32 + c) * 128 + 64 + f, fl);
        z1[3] += hv * ldw(u1, ((kh * 5 + kw) * 32 + c) * 128 + 96 + f, fl);
      } } }
  float c0 = hsig(z0[0]) * fmaxf(z0[2], 0.f);
  float c1 = hsig(z1[1]) * c0 + hsig(z1[0]) * fmaxf(z1[2], 0.f);
  float hs = hsig(z1[3]) * fmaxf(c1, 0.f);
  float hk = pr(h1a, (((size_t)b * 64 + y) * 64 + x) * 32 + f, 2097152);
  float d = fabsf(hs - hk) / (0.08f + fabsf(hs));
  atomicMax(&stat[4], __float_as_uint(d));
}

__global__ void chk6(const u16* hist, const float* gap, u32* stat) {
  int tid = threadIdx.x;
  int b = (tid & 3) * 5, f = (tid * 11) & 31;
  float s = 0.f;
  for (int t = 0; t < 16; t++)
    for (int p = 0; p < 256; p++)
      s += pr(hist, (size_t)t * 262144 + ((size_t)b * 256 + p) * 32 + f, 131072);
  float d = fabsf(s - gap[b * 32 + f]) / (1.f + fabsf(s));
  atomicMax(&stat[5], __float_as_uint(d));
}

__global__ void chk7(const float* gap, const void* wd, const void* bd,
                     const float* out, const int* dflag, u32* stat) {
  __shared__ float sg[32];
  __shared__ float lg[4096];
  __shared__ float red[256];
  int tid = threadIdx.x, fl = *dflag;
  if (tid < 32) sg[tid] = gap[tid] * (1.0f / 4096.0f);
  __syncthreads();
  float lmax = -1e30f;
  for (int i = 0; i < 16; i++) {
    int o = i * 256 + tid;
    float s = ldf(bd, o, fl);
    for (int f = 0; f < 32; f++) s += sg[f] * ldf(wd, f * 4096 + o, fl);
    lg[o] = s; lmax = fmaxf(lmax, s);
  }
  red[tid] = lmax; __syncthreads();
  for (int st = 128; st > 0; st >>= 1) { if (tid < st) red[tid] = fmaxf(red[tid], red[tid + st]); __syncthreads(); }
  float M = red[0]; __syncthreads();
  float ls = 0.f;
  for (int i = 0; i < 16; i++) ls += expf(lg[i * 256 + tid] - M);
  red[tid] = ls; __syncthreads();
  for (int st = 128; st > 0; st >>= 1) { if (tid < st) red[tid] += red[tid + st]; __syncthreads(); }
  float S = red[0];
  float dmax = 0.f;
  for (int i = 0; i < 16; i++) {
    int o = i * 256 + tid;
    float p = expf(lg[o] - M) / S;
    float pk = out[o];
    dmax = fmaxf(dmax, fabsf(p - pk) / (1e-4f + p));
  }
  atomicMax(&stat[6], __float_as_uint(dmax));
}

__global__ void verdict(const u32* stat, float* out, int n) {
  const float tol[7] = {0.05f, 0.05f, 0.05f, 0.05f, 0.08f, 0.02f, 0.05f};
  int s = -1; float dv = 0.f;
  for (int i = 0; i < 7; i++) {
    float d = __uint_as_float(stat[i]);
    if (!(d <= tol[i])) { s = i; dv = d; break; }
  }
  if (s < 0) return;
  float sent = 10.f * (s + 1) + fminf(9.f, dv);
  int i = blockIdx.x * 256 + threadIdx.x;
  if (i < n) out[i] = sent;
}

// ---- GAP-scale + dense(32->4096) + softmax; fp32 output ----
__global__ void head(const float* __restrict__ gap, const void* __restrict__ wd,
                     const void* __restrict__ bd, float* __restrict__ out,
                     const int* __restrict__ dflag) {
  int b = blockIdx.x, tid = threadIdx.x;
  int fl = *dflag;
  __shared__ float sg[32];
  __shared__ float red[256];
  if (tid < 32) sg[tid] = gap[b * 32 + tid] * (1.0f / 4096.0f);
  __syncthreads();
  float lg[16];
  float lmax = -1e30f;
#pragma unroll
  for (int i = 0; i < 16; i++) {
    int o = i * 256 + tid;
    float s = ldf(bd, o, fl);
#pragma unroll
    for (int f = 0; f < 32; f++) s += sg[f] * ldf(wd, f * 4096 + o, fl);
    lg[i] = s; lmax = fmaxf(lmax, s);
  }
  red[tid] = lmax; __syncthreads();
  for (int st = 128; st > 0; st >>= 1) { if (tid < st) red[tid] = fmaxf(red[tid], red[tid + st]); __syncthreads(); }
  float M = red[0]; __syncthreads();
  float ls = 0.f;
#pragma unroll
  for (int i = 0; i < 16; i++) { lg[i] = expf(lg[i] - M); ls += lg[i]; }
  red[tid] = ls; __syncthreads();
  for (int st = 128; st > 0; st >>= 1) { if (tid < st) red[tid] += red[tid + st]; __syncthreads(); }
  float inv = 1.0f / red[0];
#pragma unroll
  for (int i = 0; i < 16; i++) out[b * 4096 + i * 256 + tid] = lg[i] * inv;
}

extern "C" void kernel_launch(void* const* d_in, const int* in_sizes, int n_in,
                              void* d_out, int out_size, void* d_ws, size_t ws_size,
                              hipStream_t stream)
{
  const void* x   = d_in[0];
  const void* k1  = d_in[1];
  const void* u1  = d_in[2];
  const void* b1  = d_in[3];
  const void* g1  = d_in[4];
  const void* be1 = d_in[5];
  const void* m1  = d_in[6];
  const void* v1  = d_in[7];
  const void* k2  = d_in[8];
  const void* u2  = d_in[9];
  const void* b2  = d_in[10];
  const void* g2  = d_in[11];
  const void* be2 = d_in[12];
  const void* m2  = d_in[13];
  const void* v2  = d_in[14];
  const void* k3  = d_in[15];
  const void* u3  = d_in[16];
  const void* b3  = d_in[17];
  const void* wd  = d_in[18];
  const void* bd  = d_in[19];
  float* out = (float*)d_out;   // reference output dtype is float32

  char* ws = (char*)d_ws;
  size_t off = 0;
  auto alloc = [&](size_t bytes) -> char* {
    char* p = ws + off; off = (off + bytes + 255) & ~(size_t)255; return p;
  };
  // all activation u16 buffers have 2 planes (hi, lo), plane stride = N elems
  float* c1  = (float*)alloc(2097152 * 4);
  float* c2  = (float*)alloc(524288 * 4);
  float* c3  = (float*)alloc(131072 * 4);
  u16*   h1a = (u16*)alloc(2097152 * 2 * 2);
  u16*   h2a = (u16*)alloc(524288 * 2 * 2);
  u16*   h3a = (u16*)alloc(131072 * 2 * 2);
  float* gap = (float*)alloc(512 * 4);
  int*   dflag = (int*)alloc(64);        // [0]=dtype; stat[0..6] at +8
  u32*   stat  = (u32*)(dflag + 2);
  size_t zero_bytes = off;               // everything above starts at 0
  u16* h1b = (u16*)alloc(2097152 * 2 * 2);
  u16* h2b = (u16*)alloc(524288 * 2 * 2);
  u16* hist= (u16*)alloc(16 * 262144 * 2);   // h3 per-t history (2 planes/t)
  u16* p1  = (u16*)alloc(524288 * 2 * 2);
  u16* p2  = (u16*)alloc(131072 * 2 * 2);
  u16* xc  = (u16*)alloc(1048576 * 2 * 2);
  u16* W1x = (u16*)alloc(4096 * 2);
  u16* W1u = (u16*)alloc(102400 * 2);
  u16* W2k = (u16*)alloc(102400 * 2);
  u16* W2u = (u16*)alloc(102400 * 2);
  u16* W3k = (u16*)alloc(36864 * 2);
  u16* W3u = (u16*)alloc(36864 * 2);

  if (ws_size < off) {
    fillv<<<dim3((out_size + 255) / 256), 256, 0, stream>>>(out, out_size, 0.5f);
    return;
  }

  int nz = (int)(zero_bytes / 16);
  zero_ws<<<dim3((nz + 255) / 256), 256, 0, stream>>>((int4*)ws, nz);
  detect_dtype<<<1, 256, 0, stream>>>(x, dflag);
  canon_x<<<4096, 256, 0, stream>>>(x, xc, dflag, 1048576);
  repack_x<<<2, 256, 0, stream>>>(k1, W1x, dflag);
  repack_w<<<50, 256, 0, stream>>>(u1, W1u, 25, dflag);
  repack_w<<<50, 256, 0, stream>>>(k2, W2k, 25, dflag);
  repack_w<<<50, 256, 0, stream>>>(u2, W2u, 25, dflag);
  repack_w<<<18, 256, 0, stream>>>(k3, W3k, 9, dflag);
  repack_w<<<18, 256, 0, stream>>>(u3, W3u, 9, dflag);

  for (int t = 0; t < 16; ++t) {
    const u16* h1i = (t & 1) ? h1b : h1a; u16* h1o = (t & 1) ? h1a : h1b;
    const u16* h2i = (t & 1) ? h2b : h2a; u16* h2o = (t & 1) ? h2a : h2b;
    const u16* h3i = (t == 0) ? h3a : (hist + (size_t)(t - 1) * 262144);
    u16* h3o = hist + (size_t)t * 262144;
    lstm_step<5, 0, 64, 64><<<dim3(32, 16), 256, 0, stream>>>(
        xc + (size_t)t * 4096, 65536, 1048576, W1x, W1u, h1i, 2097152, h1o, c1,
        b1, g1, be1, m1, v1, p1, 524288, nullptr, dflag);
    if (t == 1)
      chk5<<<1, 64, 0, stream>>>(xc, k1, u1, b1, h1b, h1a, dflag, stat);
    lstm_step<5, 1, 32, 32><<<dim3(8, 16), 256, 0, stream>>>(
        p1, 32768, 524288, W2k, W2u, h2i, 524288, h2o, c2,
        b2, g2, be2, m2, v2, p2, 131072, nullptr, dflag);
    lstm_step<3, 2, 16, 16><<<dim3(2, 16), 256, 0, stream>>>(
        p2, 8192, 131072, W3k, W3u, h3i, 131072, h3o, c3,
        b3, nullptr, nullptr, nullptr, nullptr, nullptr, 0, gap, dflag);
    if (t == 0) {
      chk1<<<1, 64, 0, stream>>>(xc, k1, b1, h1b, dflag, stat);
      chk2<<<1, 64, 0, stream>>>(h1b, g1, be1, m1, v1, p1, dflag, stat);
      chk3<<<1, 64, 0, stream>>>(p1, k2, b2, h2b, dflag, stat);
      chk4<<<1, 64, 0, stream>>>(p2, k3, b3, hist, dflag, stat);
    }
  }
  chk6<<<1, 64, 0, stream>>>(hist, gap, stat);
  head<<<16, 256, 0, stream>>>(gap, wd, bd, out, dflag);
  chk7<<<1, 256, 0, stream>>>(gap, wd, bd, out, dflag, stat);
  verdict<<<256, 256, 0, stream>>>(stat, out, 65536);
}

// Round 8
// 1920.155 us; speedup vs baseline: 1.6621x; 1.6621x over previous
//
#include <hip/hip_runtime.h>

typedef unsigned short u16;
typedef unsigned int u32;
typedef __attribute__((ext_vector_type(8))) short bf16x8;
typedef __attribute__((ext_vector_type(4))) float f32x4;

__device__ __forceinline__ float b2f(u16 h) {
  union { float f; unsigned u; } v; v.u = ((unsigned)h) << 16; return v.f;
}
__device__ __forceinline__ u16 f2b(float f) {
  union { float f; unsigned u; } v; v.f = f;
  unsigned r = v.u + 0x7fffu + ((v.u >> 16) & 1u);
  return (u16)(r >> 16);
}
__device__ __forceinline__ float hsig(float z) {
  return fminf(fmaxf(z * 0.16666667f + 0.5f, 0.f), 1.f);
}
// dtype-adaptive scalar load: flag=1 -> bf16, flag=0 -> fp32
__device__ __forceinline__ float ldf(const void* p, int i, int flag) {
  return flag ? b2f(((const u16*)p)[i]) : ((const float*)p)[i];
}

__global__ void detect_dtype(const void* x, int* dflag) {
  __shared__ int cnt;
  if (threadIdx.x == 0) cnt = 0;
  __syncthreads();
  const u32* w = (const u32*)x;
  int c = 0;
  for (int i = threadIdx.x; i < 512; i += 256) {
    u32 e = (w[i] >> 7) & 0xFFu;
    if (e >= 100 && e < 130) c++;
  }
  atomicAdd(&cnt, c);
  __syncthreads();
  if (threadIdx.x == 0) *dflag = (cnt >= 256) ? 1 : 0;
}

// canonicalize x to hi/lo bf16 planes (lo = residual; 0 if input already bf16)
__global__ void canon_x(const void* src, u16* dst, const int* dflag, int n) {
  int i = blockIdx.x * 256 + threadIdx.x;
  if (i >= n) return;
  int fl = *dflag;
  float v = ldf(src, i, fl);
  u16 hi = f2b(v);
  dst[i] = hi;
  dst[i + n] = f2b(v - b2f(hi));
}

// ---------------------------------------------------------------------------
// Fused ConvLSTM step (implicit GEMM, MFMA 16x16x32 bf16) + LSTM update +
// (MODE 0/1) BN + 2x2 maxpool or (MODE 2) GAP accumulation.
// Activations are hi/lo bf16 pairs (plane strides sPL/hPL/pPL); the K-loop
// runs 2 passes (hi, lo) restaging the same LDS buffers; acc persists.
// ---------------------------------------------------------------------------
template<int KS, int MODE, int H, int W>
__global__ __launch_bounds__(256, 2)
void lstm_step(const u16* __restrict__ src, int aBStride, size_t sPL,
               const u16* __restrict__ wA, const u16* __restrict__ wU,
               const u16* __restrict__ hin, size_t hPL, u16* __restrict__ hout,
               float* __restrict__ cbuf, const void* __restrict__ bias,
               const void* __restrict__ bng, const void* __restrict__ bnb,
               const void* __restrict__ bnm, const void* __restrict__ bnv,
               u16* __restrict__ pooled, size_t pPL, float* __restrict__ gap,
               const int* __restrict__ dflag)
{
  constexpr int PAD = KS / 2;
  constexpr int TW = 8 + 2 * PAD;
  constexpr int TH = 16 + 2 * PAD;
  constexpr int KK = KS * KS;
  constexpr int KT = (MODE == 0) ? (KK + 1) : (2 * KK);
  constexpr int SSTR = 40;

  __shared__ __align__(16) u16 sH[TH * TW * SSTR];
  __shared__ __align__(16) u16 sA[(MODE == 0) ? (TH * TW) : (TH * TW * SSTR)];
  __shared__ __align__(16) u16 wbuf[2][4096];
  __shared__ float sgap[32];

  const int tid = threadIdx.x;
  const int b = blockIdx.y;
  constexpr int TXT = W / 8;
  const int bx0 = (blockIdx.x % TXT) * 8;
  const int gy0 = (blockIdx.x / TXT) * 16;

  const int w = tid >> 6, lane = tid & 63;
  const int j = w & 1, R0 = (w >> 1) * 8;
  const int q = lane >> 4, col = lane & 15;
  const int my = (lane >> 3) & 1, mx = lane & 7;

  if (tid < 32) sgap[tid] = 0.f;

  auto stageH = [&](int pl) {
    const u16* hsrc = hin + (size_t)pl * hPL;
    for (int i = tid; i < TH * TW * 4; i += 256) {
      int p = i >> 2, ch = i & 3;
      int sy = p / TW, sx = p - sy * TW;
      int gy = gy0 + sy - PAD, gx = bx0 + sx - PAD;
      int4 v; v.x = v.y = v.z = v.w = 0;
      if (gy >= 0 && gy < H && gx >= 0 && gx < W)
        v = *(const int4*)(hsrc + (((size_t)(b * H + gy) * W + gx) << 5) + ch * 8);
      *(int4*)(&sH[p * SSTR + ch * 8]) = v;
    }
  };
  auto stageS = [&](int pl) {
    const u16* asrc = src + (size_t)pl * sPL;
    if (MODE == 0) {
      for (int i = tid; i < TH * TW; i += 256) {
        int sy = i / TW, sx = i - sy * TW;
        int gy = gy0 + sy - PAD, gx = bx0 + sx - PAD;
        u16 v = 0;
        if (gy >= 0 && gy < H && gx >= 0 && gx < W)
          v = asrc[(size_t)b * aBStride + gy * W + gx];
        sA[i] = v;
      }
    } else {
      for (int i = tid; i < TH * TW * 4; i += 256) {
        int p = i >> 2, ch = i & 3;
        int sy = p / TW, sx = p - sy * TW;
        int gy = gy0 + sy - PAD, gx = bx0 + sx - PAD;
        int4 v; v.x = v.y = v.z = v.w = 0;
        if (gy >= 0 && gy < H && gx >= 0 && gx < W)
          v = *(const int4*)(asrc + (size_t)b * aBStride + (((size_t)gy * W + gx) << 5) + ch * 8);
        *(int4*)(&sA[p * SSTR + ch * 8]) = v;
      }
    }
  };

  auto wsel = [&](int kt) -> const u16* {
    if (MODE == 0) return (kt == 0) ? wA : (wU + (kt - 1) * 4096);
    return (kt < KK) ? (wA + kt * 4096) : (wU + (kt - KK) * 4096);
  };
  {
    const u16* wsrc = wsel(0);
    int4 a0 = *(const int4*)(wsrc + tid * 16);
    int4 a1 = *(const int4*)(wsrc + tid * 16 + 8);
    *(int4*)(&wbuf[0][tid * 16]) = a0;
    *(int4*)(&wbuf[0][tid * 16 + 8]) = a1;
  }
  stageH(0); stageS(0);
  __syncthreads();

  f32x4 acc[4][4] = {};
  int abase[4];
#pragma unroll
  for (int mt = 0; mt < 4; mt++)
    abase[mt] = ((R0 + 2 * mt + my) * TW + mx) * SSTR + q * 8;

  constexpr int KT2 = 2 * KT;
  for (int i = 0; i < KT2; ++i) {
    if (i == KT) {            // pass boundary: restage lo planes
      stageH(1); stageS(1);
      __syncthreads();
    }
    const int kt = (i < KT) ? i : i - KT;
    const bool pf = (i + 1) < KT2;
    const int nkt = ((i + 1) < KT) ? (i + 1) : (i + 1 - KT);
    int4 wn0, wn1;
    if (pf) {
      const u16* wsrc = wsel(nkt);
      wn0 = *(const int4*)(wsrc + tid * 16);
      wn1 = *(const int4*)(wsrc + tid * 16 + 8);
    }
    bf16x8 a[4];
    if (MODE == 0 && kt == 0) {
#pragma unroll
      for (int mt = 0; mt < 4; mt++) {
        union { bf16x8 v; u16 e[8]; } u;
#pragma unroll
        for (int jj = 0; jj < 8; jj++) {
          int k = q * 8 + jj;
          u16 val = 0;
          if (k < KK) {
            int kh = k / KS, kw = k - kh * KS;
            val = sA[(R0 + 2 * mt + my + kh) * TW + (mx + kw)];
          }
          u.e[jj] = val;
        }
        a[mt] = u.v;
      }
    } else {
      int tap; const u16* s;
      if (MODE == 0)      { tap = kt - 1;  s = sH; }
      else if (kt < KK)   { tap = kt;      s = sA; }
      else                { tap = kt - KK; s = sH; }
      const int kh = tap / KS, kw = tap - kh * KS;
      const int aoff = (kh * TW + kw) * SSTR;
#pragma unroll
      for (int mt = 0; mt < 4; mt++)
        a[mt] = *(const bf16x8*)(s + abase[mt] + aoff);
    }
    const u16* wb = wbuf[i & 1];
    bf16x8 bf[4];
#pragma unroll
    for (int g = 0; g < 4; g++)
      bf[g] = *(const bf16x8*)(wb + ((j + 2 * g) * 64 + lane) * 8);
#pragma unroll
    for (int mt = 0; mt < 4; mt++)
#pragma unroll
      for (int g = 0; g < 4; g++)
        acc[mt][g] = __builtin_amdgcn_mfma_f32_16x16x32_bf16(a[mt], bf[g], acc[mt][g], 0, 0, 0);
    if (pf) {
      *(int4*)(&wbuf[(i + 1) & 1][tid * 16]) = wn0;
      *(int4*)(&wbuf[(i + 1) & 1][tid * 16 + 8]) = wn1;
    }
    __syncthreads();
  }

  const int fl = *dflag;
  const int f = j * 16 + col;
  const float bi  = ldf(bias, f, fl);
  const float bff = ldf(bias, 32 + f, fl);
  const float bg  = ldf(bias, 64 + f, fl);
  const float bo  = ldf(bias, 96 + f, fl);
  float sc = 0.f, sh = 0.f;
  if (MODE < 2) {
    sc = ldf(bng, f, fl) * rsqrtf(ldf(bnv, f, fl) + 1e-3f);
    sh = ldf(bnb, f, fl) - ldf(bnm, f, fl) * sc;
  }
  const int oy = q >> 1;
  const int ox = (q & 1) * 4;
  float gsum = 0.f;
#pragma unroll
  for (int mt = 0; mt < 4; mt++) {
    const int y = gy0 + R0 + 2 * mt + oy;
    const size_t base = (((size_t)(b * H + y) * W + (bx0 + ox)) << 5) + f;
    float bnp[4];
#pragma unroll
    for (int r = 0; r < 4; r++) {
      float zi = acc[mt][0][r] + bi;
      float zf = acc[mt][1][r] + bff;
      float zg = acc[mt][2][r] + bg;
      float zo = acc[mt][3][r] + bo;
      float ig = hsig(zi), fg = hsig(zf), og = hsig(zo);
      float gg = fmaxf(zg, 0.f);
      size_t idx = base + ((size_t)r << 5);
      float cold = cbuf[idx];
      float cn = fg * cold + ig * gg;
      cbuf[idx] = cn;
      float hn = og * fmaxf(cn, 0.f);
      u16 hhi = f2b(hn);
      hout[idx] = hhi;
      hout[idx + hPL] = f2b(hn - b2f(hhi));
      if (MODE < 2) bnp[r] = hn * sc + sh; else gsum += hn;
    }
    if (MODE < 2) {
      float p0 = fmaxf(bnp[0], bnp[1]);
      float p1 = fmaxf(bnp[2], bnp[3]);
      p0 = fmaxf(p0, __shfl_xor(p0, 32));
      p1 = fmaxf(p1, __shfl_xor(p1, 32));
      if (q < 2) {
        const int py = (gy0 + R0 + 2 * mt) >> 1;
        const int px = (bx0 >> 1) + (q & 1) * 2;
        size_t pb = (((size_t)(b * (H / 2) + py) * (W / 2) + px) << 5) + f;
        u16 phi = f2b(p0);
        pooled[pb] = phi;
        pooled[pb + pPL] = f2b(p0 - b2f(phi));
        u16 qhi = f2b(p1);
        pooled[pb + 32] = qhi;
        pooled[pb + 32 + pPL] = f2b(p1 - b2f(qhi));
      }
    }
  }
  if (MODE == 2) {
    atomicAdd(&sgap[f], gsum);
    __syncthreads();
    if (tid < 32) atomicAdd(&gap[b * 32 + tid], sgap[tid]);
  }
}

__global__ void repack_w(const void* __restrict__ src, u16* __restrict__ dst,
                         int taps, const int* __restrict__ dflag) {
  int i = blockIdx.x * 256 + threadIdx.x;
  if (i >= taps * 512) return;
  int fl = *dflag;
  int l = i & 63, nt = (i >> 6) & 7, tap = i >> 9;
  int q = l >> 4, col = l & 15;
  u16 tmp[8];
#pragma unroll
  for (int j = 0; j < 8; j++)
    tmp[j] = f2b(ldf(src, (tap * 32 + q * 8 + j) * 128 + nt * 16 + col, fl));
#pragma unroll
  for (int j = 0; j < 8; j++) dst[i * 8 + j] = tmp[j];
}
__global__ void repack_x(const void* __restrict__ src, u16* __restrict__ dst,
                         const int* __restrict__ dflag) {
  int i = blockIdx.x * 256 + threadIdx.x;
  if (i >= 512) return;
  int fl = *dflag;
  int l = i & 63, nt = (i >> 6) & 7;
  int q = l >> 4, col = l & 15;
#pragma unroll
  for (int j = 0; j < 8; j++) {
    int k = q * 8 + j;
    dst[i * 8 + j] = (k < 25) ? f2b(ldf(src, k * 128 + nt * 16 + col, fl)) : (u16)0;
  }
}

__global__ void zero_ws(int4* p, int n) {
  int i = blockIdx.x * 256 + threadIdx.x;
  if (i < n) { int4 z; z.x = z.y = z.z = z.w = 0; p[i] = z; }
}
__global__ void fillv(float* out, int n, float v) {
  int i = blockIdx.x * 256 + threadIdx.x;
  if (i < n) out[i] = v;
}

// ---- dense(32->4096) logits: one thread per (b,o); full-device ----
__global__ void logits_k(const float* __restrict__ gap, const void* __restrict__ wd,
                         const void* __restrict__ bd, float* __restrict__ lg,
                         const int* __restrict__ dflag) {
  int i = blockIdx.x * 256 + threadIdx.x;      // 65536 = 16 b x 4096 o
  int b = i >> 12, o = i & 4095;
  int fl = *dflag;
  float s = ldf(bd, o, fl);
  const float scl = 1.0f / 4096.0f;
#pragma unroll
  for (int f = 0; f < 32; f++)
    s += gap[b * 32 + f] * scl * ldf(wd, f * 4096 + o, fl);
  lg[i] = s;
}

// ---- per-batch softmax over 4096 logits ----
__global__ void softmax_k(const float* __restrict__ lg, float* __restrict__ out) {
  int b = blockIdx.x, tid = threadIdx.x;
  __shared__ float red[256];
  float v[16];
  float lmax = -1e30f;
#pragma unroll
  for (int i = 0; i < 16; i++) {
    v[i] = lg[b * 4096 + i * 256 + tid];
    lmax = fmaxf(lmax, v[i]);
  }
  red[tid] = lmax; __syncthreads();
  for (int st = 128; st > 0; st >>= 1) { if (tid < st) red[tid] = fmaxf(red[tid], red[tid + st]); __syncthreads(); }
  float M = red[0]; __syncthreads();
  float ls = 0.f;
#pragma unroll
  for (int i = 0; i < 16; i++) { v[i] = expf(v[i] - M); ls += v[i]; }
  red[tid] = ls; __syncthreads();
  for (int st = 128; st > 0; st >>= 1) { if (tid < st) red[tid] += red[tid + st]; __syncthreads(); }
  float inv = 1.0f / red[0];
#pragma unroll
  for (int i = 0; i < 16; i++) out[b * 4096 + i * 256 + tid] = v[i] * inv;
}

extern "C" void kernel_launch(void* const* d_in, const int* in_sizes, int n_in,
                              void* d_out, int out_size, void* d_ws, size_t ws_size,
                              hipStream_t stream)
{
  const void* x   = d_in[0];
  const void* k1  = d_in[1];
  const void* u1  = d_in[2];
  const void* b1  = d_in[3];
  const void* g1  = d_in[4];
  const void* be1 = d_in[5];
  const void* m1  = d_in[6];
  const void* v1  = d_in[7];
  const void* k2  = d_in[8];
  const void* u2  = d_in[9];
  const void* b2  = d_in[10];
  const void* g2  = d_in[11];
  const void* be2 = d_in[12];
  const void* m2  = d_in[13];
  const void* v2  = d_in[14];
  const void* k3  = d_in[15];
  const void* u3  = d_in[16];
  const void* b3  = d_in[17];
  const void* wd  = d_in[18];
  const void* bd  = d_in[19];
  float* out = (float*)d_out;   // reference output dtype is float32

  char* ws = (char*)d_ws;
  size_t off = 0;
  auto alloc = [&](size_t bytes) -> char* {
    char* p = ws + off; off = (off + bytes + 255) & ~(size_t)255; return p;
  };
  // activation u16 buffers carry 2 planes (hi, lo); plane stride = N elems
  float* c1  = (float*)alloc(2097152 * 4);
  float* c2  = (float*)alloc(524288 * 4);
  float* c3  = (float*)alloc(131072 * 4);
  u16*   h1a = (u16*)alloc(2097152 * 2 * 2);
  u16*   h2a = (u16*)alloc(524288 * 2 * 2);
  u16*   h3a = (u16*)alloc(131072 * 2 * 2);
  float* gap = (float*)alloc(512 * 4);
  int*   dflag = (int*)alloc(64);
  size_t zero_bytes = off;               // everything above starts at 0
  u16* h1b = (u16*)alloc(2097152 * 2 * 2);
  u16* h2b = (u16*)alloc(524288 * 2 * 2);
  u16* h3b = (u16*)alloc(131072 * 2 * 2);
  u16* p1  = (u16*)alloc(524288 * 2 * 2);
  u16* p2  = (u16*)alloc(131072 * 2 * 2);
  u16* xc  = (u16*)alloc(1048576 * 2 * 2);
  float* lgbuf = (float*)alloc(65536 * 4);
  u16* W1x = (u16*)alloc(4096 * 2);
  u16* W1u = (u16*)alloc(102400 * 2);
  u16* W2k = (u16*)alloc(102400 * 2);
  u16* W2u = (u16*)alloc(102400 * 2);
  u16* W3k = (u16*)alloc(36864 * 2);
  u16* W3u = (u16*)alloc(36864 * 2);

  if (ws_size < off) {
    fillv<<<dim3((out_size + 255) / 256), 256, 0, stream>>>(out, out_size, 0.5f);
    return;
  }

  int nz = (int)(zero_bytes / 16);
  zero_ws<<<dim3((nz + 255) / 256), 256, 0, stream>>>((int4*)ws, nz);
  detect_dtype<<<1, 256, 0, stream>>>(x, dflag);
  canon_x<<<4096, 256, 0, stream>>>(x, xc, dflag, 1048576);
  repack_x<<<2, 256, 0, stream>>>(k1, W1x, dflag);
  repack_w<<<50, 256, 0, stream>>>(u1, W1u, 25, dflag);
  repack_w<<<50, 256, 0, stream>>>(k2, W2k, 25, dflag);
  repack_w<<<50, 256, 0, stream>>>(u2, W2u, 25, dflag);
  repack_w<<<18, 256, 0, stream>>>(k3, W3k, 9, dflag);
  repack_w<<<18, 256, 0, stream>>>(u3, W3u, 9, dflag);

  for (int t = 0; t < 16; ++t) {
    const u16* h1i = (t & 1) ? h1b : h1a; u16* h1o = (t & 1) ? h1a : h1b;
    const u16* h2i = (t & 1) ? h2b : h2a; u16* h2o = (t & 1) ? h2a : h2b;
    const u16* h3i = (t & 1) ? h3b : h3a; u16* h3o = (t & 1) ? h3a : h3b;
    lstm_step<5, 0, 64, 64><<<dim3(32, 16), 256, 0, stream>>>(
        xc + (size_t)t * 4096, 65536, 1048576, W1x, W1u, h1i, 2097152, h1o, c1,
        b1, g1, be1, m1, v1, p1, 524288, nullptr, dflag);
    lstm_step<5, 1, 32, 32><<<dim3(8, 16), 256, 0, stream>>>(
        p1, 32768, 524288, W2k, W2u, h2i, 524288, h2o, c2,
        b2, g2, be2, m2, v2, p2, 131072, nullptr, dflag);
    lstm_step<3, 2, 16, 16><<<dim3(2, 16), 256, 0, stream>>>(
        p2, 8192, 131072, W3k, W3u, h3i, 131072, h3o, c3,
        b3, nullptr, nullptr, nullptr, nullptr, nullptr, 0, gap, dflag);
  }
  logits_k<<<256, 256, 0, stream>>>(gap, wd, bd, lgbuf, dflag);
  softmax_k<<<16, 256, 0, stream>>>(lgbuf, out);
}

// Round 9
// 1653.584 us; speedup vs baseline: 1.9300x; 1.1612x over previous
//
#include <hip/hip_runtime.h>

typedef unsigned short u16;
typedef unsigned int u32;
typedef __attribute__((ext_vector_type(8))) short bf16x8;
typedef __attribute__((ext_vector_type(4))) float f32x4;

__device__ __forceinline__ float b2f(u16 h) {
  union { float f; unsigned u; } v; v.u = ((unsigned)h) << 16; return v.f;
}
__device__ __forceinline__ u16 f2b(float f) {
  union { float f; unsigned u; } v; v.f = f;
  unsigned r = v.u + 0x7fffu + ((v.u >> 16) & 1u);
  return (u16)(r >> 16);
}
__device__ __forceinline__ float hsig(float z) {
  return fminf(fmaxf(z * 0.16666667f + 0.5f, 0.f), 1.f);
}
// dtype-adaptive scalar load: flag=1 -> bf16, flag=0 -> fp32
__device__ __forceinline__ float ldf(const void* p, int i, int flag) {
  return flag ? b2f(((const u16*)p)[i]) : ((const float*)p)[i];
}

__global__ void detect_dtype(const void* x, int* dflag) {
  __shared__ int cnt;
  if (threadIdx.x == 0) cnt = 0;
  __syncthreads();
  const u32* w = (const u32*)x;
  int c = 0;
  for (int i = threadIdx.x; i < 512; i += 256) {
    u32 e = (w[i] >> 7) & 0xFFu;
    if (e >= 100 && e < 130) c++;
  }
  atomicAdd(&cnt, c);
  __syncthreads();
  if (threadIdx.x == 0) *dflag = (cnt >= 256) ? 1 : 0;
}

// canonicalize x to hi/lo bf16 planes (lo = residual; 0 if input already bf16)
__global__ void canon_x(const void* src, u16* dst, const int* dflag, int n) {
  int i = blockIdx.x * 256 + threadIdx.x;
  if (i >= n) return;
  int fl = *dflag;
  float v = ldf(src, i, fl);
  u16 hi = f2b(v);
  dst[i] = hi;
  dst[i + n] = f2b(v - b2f(hi));
}

// ---------------------------------------------------------------------------
// Fused ConvLSTM step (implicit GEMM, MFMA 16x16x32 bf16) + LSTM update +
// (MODE 0/1) BN + 2x2 maxpool or (MODE 2) GAP accumulation.
// Activations are hi/lo bf16 pairs; the K-loop runs 2 passes (hi, lo)
// restaging the same LDS buffers; acc persists.
// Weights are read straight from global (repacked fragment-contiguous,
// L2-resident) with a 1-deep register prefetch -> the K-loop is BARRIER-FREE
// (only 2 stage barriers per pass). This removes the ~100 per-tap barriers
// that made the kernel latency-bound at 5% occupancy (round-8 counters).
// ---------------------------------------------------------------------------
template<int KS, int MODE, int H, int W>
__global__ __launch_bounds__(256, 2)
void lstm_step(const u16* __restrict__ src, int aBStride, size_t sPL,
               const u16* __restrict__ wA, const u16* __restrict__ wU,
               const u16* __restrict__ hin, size_t hPL, u16* __restrict__ hout,
               float* __restrict__ cbuf, const void* __restrict__ bias,
               const void* __restrict__ bng, const void* __restrict__ bnb,
               const void* __restrict__ bnm, const void* __restrict__ bnv,
               u16* __restrict__ pooled, size_t pPL, float* __restrict__ gap,
               const int* __restrict__ dflag)
{
  constexpr int PAD = KS / 2;
  constexpr int TW = 8 + 2 * PAD;
  constexpr int TH = 16 + 2 * PAD;
  constexpr int KK = KS * KS;
  constexpr int KT = (MODE == 0) ? (KK + 1) : (2 * KK);
  constexpr int SSTR = 40;

  __shared__ __align__(16) u16 sH[TH * TW * SSTR];
  __shared__ __align__(16) u16 sA[(MODE == 0) ? (TH * TW) : (TH * TW * SSTR)];
  __shared__ float sgap[32];

  const int tid = threadIdx.x;
  const int b = blockIdx.y;
  constexpr int TXT = W / 8;
  const int bx0 = (blockIdx.x % TXT) * 8;
  const int gy0 = (blockIdx.x / TXT) * 16;

  const int w = tid >> 6, lane = tid & 63;
  const int j = w & 1, R0 = (w >> 1) * 8;
  const int q = lane >> 4, col = lane & 15;
  const int my = (lane >> 3) & 1, mx = lane & 7;

  if (tid < 32) sgap[tid] = 0.f;

  auto stageH = [&](int pl) {
    const u16* hsrc = hin + (size_t)pl * hPL;
    for (int i = tid; i < TH * TW * 4; i += 256) {
      int p = i >> 2, ch = i & 3;
      int sy = p / TW, sx = p - sy * TW;
      int gy = gy0 + sy - PAD, gx = bx0 + sx - PAD;
      int4 v; v.x = v.y = v.z = v.w = 0;
      if (gy >= 0 && gy < H && gx >= 0 && gx < W)
        v = *(const int4*)(hsrc + (((size_t)(b * H + gy) * W + gx) << 5) + ch * 8);
      *(int4*)(&sH[p * SSTR + ch * 8]) = v;
    }
  };
  auto stageS = [&](int pl) {
    const u16* asrc = src + (size_t)pl * sPL;
    if (MODE == 0) {
      for (int i = tid; i < TH * TW; i += 256) {
        int sy = i / TW, sx = i - sy * TW;
        int gy = gy0 + sy - PAD, gx = bx0 + sx - PAD;
        u16 v = 0;
        if (gy >= 0 && gy < H && gx >= 0 && gx < W)
          v = asrc[(size_t)b * aBStride + gy * W + gx];
        sA[i] = v;
      }
    } else {
      for (int i = tid; i < TH * TW * 4; i += 256) {
        int p = i >> 2, ch = i & 3;
        int sy = p / TW, sx = p - sy * TW;
        int gy = gy0 + sy - PAD, gx = bx0 + sx - PAD;
        int4 v; v.x = v.y = v.z = v.w = 0;
        if (gy >= 0 && gy < H && gx >= 0 && gx < W)
          v = *(const int4*)(asrc + (size_t)b * aBStride + (((size_t)gy * W + gx) << 5) + ch * 8);
        *(int4*)(&sA[p * SSTR + ch * 8]) = v;
      }
    }
  };

  auto wsel = [&](int kt) -> const u16* {
    if (MODE == 0) return (kt == 0) ? wA : (wU + (kt - 1) * 4096);
    return (kt < KK) ? (wA + kt * 4096) : (wU + (kt - KK) * 4096);
  };
  const int wfoff = lane * 8;   // lane's 16B fragment within an n-tile row

  f32x4 acc[4][4] = {};  // [m-tile][gate]
  int abase[4];
#pragma unroll
  for (int mt = 0; mt < 4; mt++)
    abase[mt] = ((R0 + 2 * mt + my) * TW + mx) * SSTR + q * 8;

  for (int pass = 0; pass < 2; ++pass) {
    if (pass == 1) __syncthreads();      // all pass-0 reads done before restage
    stageH(pass); stageS(pass);
    __syncthreads();

    bf16x8 bw[4];
    {
      const u16* w0 = wsel(0);
#pragma unroll
      for (int g = 0; g < 4; g++)
        bw[g] = *(const bf16x8*)(w0 + ((j + 2 * g) * 64) * 8 + wfoff);
    }
#pragma unroll 2
    for (int kt = 0; kt < KT; ++kt) {
      bf16x8 nw[4];
      if (kt + 1 < KT) {
        const u16* wn = wsel(kt + 1);
#pragma unroll
        for (int g = 0; g < 4; g++)
          nw[g] = *(const bf16x8*)(wn + ((j + 2 * g) * 64) * 8 + wfoff);
      }
      bf16x8 a[4];
      if (MODE == 0 && kt == 0) {
        // x-conv as GEMM over taps: A[m][k=tap]
#pragma unroll
        for (int mt = 0; mt < 4; mt++) {
          union { bf16x8 v; u16 e[8]; } u;
#pragma unroll
          for (int jj = 0; jj < 8; jj++) {
            int k = q * 8 + jj;
            u16 val = 0;
            if (k < KK) {
              int kh = k / KS, kw = k - kh * KS;
              val = sA[(R0 + 2 * mt + my + kh) * TW + (mx + kw)];
            }
            u.e[jj] = val;
          }
          a[mt] = u.v;
        }
      } else {
        int tap; const u16* s;
        if (MODE == 0)      { tap = kt - 1;  s = sH; }
        else if (kt < KK)   { tap = kt;      s = sA; }
        else                { tap = kt - KK; s = sH; }
        const int kh = tap / KS, kw = tap - kh * KS;
        const int aoff = (kh * TW + kw) * SSTR;
#pragma unroll
        for (int mt = 0; mt < 4; mt++)
          a[mt] = *(const bf16x8*)(s + abase[mt] + aoff);
      }
#pragma unroll
      for (int mt = 0; mt < 4; mt++)
#pragma unroll
        for (int g = 0; g < 4; g++)
          acc[mt][g] = __builtin_amdgcn_mfma_f32_16x16x32_bf16(a[mt], bw[g], acc[mt][g], 0, 0, 0);
#pragma unroll
      for (int g = 0; g < 4; g++) bw[g] = nw[g];
    }
  }

  // ---- epilogue: gates, state update, BN+pool / GAP ----
  const int fl = *dflag;
  const int f = j * 16 + col;
  const float bi  = ldf(bias, f, fl);
  const float bff = ldf(bias, 32 + f, fl);
  const float bg  = ldf(bias, 64 + f, fl);
  const float bo  = ldf(bias, 96 + f, fl);
  float sc = 0.f, sh = 0.f;
  if (MODE < 2) {
    sc = ldf(bng, f, fl) * rsqrtf(ldf(bnv, f, fl) + 1e-3f);
    sh = ldf(bnb, f, fl) - ldf(bnm, f, fl) * sc;
  }
  const int oy = q >> 1;
  const int ox = (q & 1) * 4;
  float gsum = 0.f;
#pragma unroll
  for (int mt = 0; mt < 4; mt++) {
    const int y = gy0 + R0 + 2 * mt + oy;
    const size_t base = (((size_t)(b * H + y) * W + (bx0 + ox)) << 5) + f;
    float bnp[4];
#pragma unroll
    for (int r = 0; r < 4; r++) {
      float zi = acc[mt][0][r] + bi;
      float zf = acc[mt][1][r] + bff;
      float zg = acc[mt][2][r] + bg;
      float zo = acc[mt][3][r] + bo;
      float ig = hsig(zi), fg = hsig(zf), og = hsig(zo);
      float gg = fmaxf(zg, 0.f);
      size_t idx = base + ((size_t)r << 5);
      float cold = cbuf[idx];
      float cn = fg * cold + ig * gg;
      cbuf[idx] = cn;
      float hn = og * fmaxf(cn, 0.f);
      u16 hhi = f2b(hn);
      hout[idx] = hhi;
      hout[idx + hPL] = f2b(hn - b2f(hhi));
      if (MODE < 2) bnp[r] = hn * sc + sh; else gsum += hn;
    }
    if (MODE < 2) {
      float p0 = fmaxf(bnp[0], bnp[1]);
      float p1 = fmaxf(bnp[2], bnp[3]);
      p0 = fmaxf(p0, __shfl_xor(p0, 32));
      p1 = fmaxf(p1, __shfl_xor(p1, 32));
      if (q < 2) {
        const int py = (gy0 + R0 + 2 * mt) >> 1;
        const int px = (bx0 >> 1) + (q & 1) * 2;
        size_t pb = (((size_t)(b * (H / 2) + py) * (W / 2) + px) << 5) + f;
        u16 phi = f2b(p0);
        pooled[pb] = phi;
        pooled[pb + pPL] = f2b(p0 - b2f(phi));
        u16 qhi = f2b(p1);
        pooled[pb + 32] = qhi;
        pooled[pb + 32 + pPL] = f2b(p1 - b2f(qhi));
      }
    }
  }
  if (MODE == 2) {
    atomicAdd(&sgap[f], gsum);
    __syncthreads();
    if (tid < 32) atomicAdd(&gap[b * 32 + tid], sgap[tid]);
  }
}

__global__ void repack_w(const void* __restrict__ src, u16* __restrict__ dst,
                         int taps, const int* __restrict__ dflag) {
  int i = blockIdx.x * 256 + threadIdx.x;
  if (i >= taps * 512) return;
  int fl = *dflag;
  int l = i & 63, nt = (i >> 6) & 7, tap = i >> 9;
  int q = l >> 4, col = l & 15;
  u16 tmp[8];
#pragma unroll
  for (int j = 0; j < 8; j++)
    tmp[j] = f2b(ldf(src, (tap * 32 + q * 8 + j) * 128 + nt * 16 + col, fl));
#pragma unroll
  for (int j = 0; j < 8; j++) dst[i * 8 + j] = tmp[j];
}
__global__ void repack_x(const void* __restrict__ src, u16* __restrict__ dst,
                         const int* __restrict__ dflag) {
  int i = blockIdx.x * 256 + threadIdx.x;
  if (i >= 512) return;
  int fl = *dflag;
  int l = i & 63, nt = (i >> 6) & 7;
  int q = l >> 4, col = l & 15;
#pragma unroll
  for (int j = 0; j < 8; j++) {
    int k = q * 8 + j;
    dst[i * 8 + j] = (k < 25) ? f2b(ldf(src, k * 128 + nt * 16 + col, fl)) : (u16)0;
  }
}

__global__ void zero_ws(int4* p, int n) {
  int i = blockIdx.x * 256 + threadIdx.x;
  if (i < n) { int4 z; z.x = z.y = z.z = z.w = 0; p[i] = z; }
}
__global__ void fillv(float* out, int n, float v) {
  int i = blockIdx.x * 256 + threadIdx.x;
  if (i < n) out[i] = v;
}

// ---- dense(32->4096) logits: one thread per (b,o); full-device ----
__global__ void logits_k(const float* __restrict__ gap, const void* __restrict__ wd,
                         const void* __restrict__ bd, float* __restrict__ lg,
                         const int* __restrict__ dflag) {
  int i = blockIdx.x * 256 + threadIdx.x;      // 65536 = 16 b x 4096 o
  int b = i >> 12, o = i & 4095;
  int fl = *dflag;
  float s = ldf(bd, o, fl);
  const float scl = 1.0f / 4096.0f;
#pragma unroll
  for (int f = 0; f < 32; f++)
    s += gap[b * 32 + f] * scl * ldf(wd, f * 4096 + o, fl);
  lg[i] = s;
}

// ---- per-batch softmax over 4096 logits ----
__global__ void softmax_k(const float* __restrict__ lg, float* __restrict__ out) {
  int b = blockIdx.x, tid = threadIdx.x;
  __shared__ float red[256];
  float v[16];
  float lmax = -1e30f;
#pragma unroll
  for (int i = 0; i < 16; i++) {
    v[i] = lg[b * 4096 + i * 256 + tid];
    lmax = fmaxf(lmax, v[i]);
  }
  red[tid] = lmax; __syncthreads();
  for (int st = 128; st > 0; st >>= 1) { if (tid < st) red[tid] = fmaxf(red[tid], red[tid + st]); __syncthreads(); }
  float M = red[0]; __syncthreads();
  float ls = 0.f;
#pragma unroll
  for (int i = 0; i < 16; i++) { v[i] = expf(v[i] - M); ls += v[i]; }
  red[tid] = ls; __syncthreads();
  for (int st = 128; st > 0; st >>= 1) { if (tid < st) red[tid] += red[tid + st]; __syncthreads(); }
  float inv = 1.0f / red[0];
#pragma unroll
  for (int i = 0; i < 16; i++) out[b * 4096 + i * 256 + tid] = v[i] * inv;
}

extern "C" void kernel_launch(void* const* d_in, const int* in_sizes, int n_in,
                              void* d_out, int out_size, void* d_ws, size_t ws_size,
                              hipStream_t stream)
{
  const void* x   = d_in[0];
  const void* k1  = d_in[1];
  const void* u1  = d_in[2];
  const void* b1  = d_in[3];
  const void* g1  = d_in[4];
  const void* be1 = d_in[5];
  const void* m1  = d_in[6];
  const void* v1  = d_in[7];
  const void* k2  = d_in[8];
  const void* u2  = d_in[9];
  const void* b2  = d_in[10];
  const void* g2  = d_in[11];
  const void* be2 = d_in[12];
  const void* m2  = d_in[13];
  const void* v2  = d_in[14];
  const void* k3  = d_in[15];
  const void* u3  = d_in[16];
  const void* b3  = d_in[17];
  const void* wd  = d_in[18];
  const void* bd  = d_in[19];
  float* out = (float*)d_out;   // reference output dtype is float32

  char* ws = (char*)d_ws;
  size_t off = 0;
  auto alloc = [&](size_t bytes) -> char* {
    char* p = ws + off; off = (off + bytes + 255) & ~(size_t)255; return p;
  };
  // activation u16 buffers carry 2 planes (hi, lo); plane stride = N elems
  float* c1  = (float*)alloc(2097152 * 4);
  float* c2  = (float*)alloc(524288 * 4);
  float* c3  = (float*)alloc(131072 * 4);
  u16*   h1a = (u16*)alloc(2097152 * 2 * 2);
  u16*   h2a = (u16*)alloc(524288 * 2 * 2);
  u16*   h3a = (u16*)alloc(131072 * 2 * 2);
  float* gap = (float*)alloc(512 * 4);
  int*   dflag = (int*)alloc(64);
  size_t zero_bytes = off;               // everything above starts at 0
  u16* h1b = (u16*)alloc(2097152 * 2 * 2);
  u16* h2b = (u16*)alloc(524288 * 2 * 2);
  u16* h3b = (u16*)alloc(131072 * 2 * 2);
  u16* p1  = (u16*)alloc(524288 * 2 * 2);
  u16* p2  = (u16*)alloc(131072 * 2 * 2);
  u16* xc  = (u16*)alloc(1048576 * 2 * 2);
  float* lgbuf = (float*)alloc(65536 * 4);
  u16* W1x = (u16*)alloc(4096 * 2);
  u16* W1u = (u16*)alloc(102400 * 2);
  u16* W2k = (u16*)alloc(102400 * 2);
  u16* W2u = (u16*)alloc(102400 * 2);
  u16* W3k = (u16*)alloc(36864 * 2);
  u16* W3u = (u16*)alloc(36864 * 2);

  if (ws_size < off) {
    fillv<<<dim3((out_size + 255) / 256), 256, 0, stream>>>(out, out_size, 0.5f);
    return;
  }

  int nz = (int)(zero_bytes / 16);
  zero_ws<<<dim3((nz + 255) / 256), 256, 0, stream>>>((int4*)ws, nz);
  detect_dtype<<<1, 256, 0, stream>>>(x, dflag);
  canon_x<<<4096, 256, 0, stream>>>(x, xc, dflag, 1048576);
  repack_x<<<2, 256, 0, stream>>>(k1, W1x, dflag);
  repack_w<<<50, 256, 0, stream>>>(u1, W1u, 25, dflag);
  repack_w<<<50, 256, 0, stream>>>(k2, W2k, 25, dflag);
  repack_w<<<50, 256, 0, stream>>>(u2, W2u, 25, dflag);
  repack_w<<<18, 256, 0, stream>>>(k3, W3k, 9, dflag);
  repack_w<<<18, 256, 0, stream>>>(u3, W3u, 9, dflag);

  for (int t = 0; t < 16; ++t) {
    const u16* h1i = (t & 1) ? h1b : h1a; u16* h1o = (t & 1) ? h1a : h1b;
    const u16* h2i = (t & 1) ? h2b : h2a; u16* h2o = (t & 1) ? h2a : h2b;
    const u16* h3i = (t & 1) ? h3b : h3a; u16* h3o = (t & 1) ? h3a : h3b;
    lstm_step<5, 0, 64, 64><<<dim3(32, 16), 256, 0, stream>>>(
        xc + (size_t)t * 4096, 65536, 1048576, W1x, W1u, h1i, 2097152, h1o, c1,
        b1, g1, be1, m1, v1, p1, 524288, nullptr, dflag);
    lstm_step<5, 1, 32, 32><<<dim3(8, 16), 256, 0, stream>>>(
        p1, 32768, 524288, W2k, W2u, h2i, 524288, h2o, c2,
        b2, g2, be2, m2, v2, p2, 131072, nullptr, dflag);
    lstm_step<3, 2, 16, 16><<<dim3(2, 16), 256, 0, stream>>>(
        p2, 8192, 131072, W3k, W3u, h3i, 131072, h3o, c3,
        b3, nullptr, nullptr, nullptr, nullptr, nullptr, 0, gap, dflag);
  }
  logits_k<<<256, 256, 0, stream>>>(gap, wd, bd, lgbuf, dflag);
  softmax_k<<<16, 256, 0, stream>>>(lgbuf, out);
}

// Round 10
// 1351.802 us; speedup vs baseline: 2.3609x; 1.2232x over previous
//
#include <hip/hip_runtime.h>

typedef unsigned short u16;
typedef unsigned int u32;
typedef __attribute__((ext_vector_type(8))) short bf16x8;
typedef __attribute__((ext_vector_type(4))) float f32x4;

__device__ __forceinline__ float b2f(u16 h) {
  union { float f; unsigned u; } v; v.u = ((unsigned)h) << 16; return v.f;
}
__device__ __forceinline__ u16 f2b(float f) {
  union { float f; unsigned u; } v; v.f = f;
  unsigned r = v.u + 0x7fffu + ((v.u >> 16) & 1u);
  return (u16)(r >> 16);
}
__device__ __forceinline__ float hsig(float z) {
  return fminf(fmaxf(z * 0.16666667f + 0.5f, 0.f), 1.f);
}
__device__ __forceinline__ float ldf(const void* p, int i, int flag) {
  return flag ? b2f(((const u16*)p)[i]) : ((const float*)p)[i];
}

__global__ void detect_dtype(const void* x, int* dflag) {
  __shared__ int cnt;
  if (threadIdx.x == 0) cnt = 0;
  __syncthreads();
  const u32* w = (const u32*)x;
  int c = 0;
  for (int i = threadIdx.x; i < 512; i += 256) {
    u32 e = (w[i] >> 7) & 0xFFu;
    if (e >= 100 && e < 130) c++;
  }
  atomicAdd(&cnt, c);
  __syncthreads();
  if (threadIdx.x == 0) *dflag = (cnt >= 256) ? 1 : 0;
}

__global__ void canon_x(const void* src, u16* dst, const int* dflag, int n) {
  int i = blockIdx.x * 256 + threadIdx.x;
  if (i >= n) return;
  int fl = *dflag;
  float v = ldf(src, i, fl);
  u16 hi = f2b(v);
  dst[i] = hi;
  dst[i + n] = f2b(v - b2f(hi));
}

// ---------------------------------------------------------------------------
// ConvLSTM step body (device function; called from the fused kernel).
// Implicit-GEMM MFMA 16x16x32 bf16; hi/lo bf16 activation pairs; 2-pass
// K-loop restaging the same LDS; barrier-free inner loop; depth-2 register
// prefetch of fragment-contiguous global weights.
// ---------------------------------------------------------------------------
template<int KS, int MODE, int H, int W>
__device__ __forceinline__
void step_body(int bxi, int b, char* dsm,
               const u16* __restrict__ src, int aBStride, size_t sPL,
               const u16* __restrict__ wA, const u16* __restrict__ wU,
               const u16* __restrict__ hin, size_t hPL, u16* __restrict__ hout,
               float* __restrict__ cbuf, const void* __restrict__ bias,
               const void* __restrict__ bng, const void* __restrict__ bnb,
               const void* __restrict__ bnm, const void* __restrict__ bnv,
               u16* __restrict__ pooled, size_t pPL, float* __restrict__ gap,
               const int* __restrict__ dflag)
{
  constexpr int PAD = KS / 2;
  constexpr int TW = 8 + 2 * PAD;
  constexpr int TH = 16 + 2 * PAD;
  constexpr int KK = KS * KS;
  constexpr int KT = (MODE == 0) ? (KK + 1) : (2 * KK);
  constexpr int SSTR = 40;

  u16* sH = (u16*)dsm;
  u16* sA = sH + TH * TW * SSTR;
  float* sgap = (float*)(sA + ((MODE == 0) ? (TH * TW + 8) : (TH * TW * SSTR)));

  const int tid = threadIdx.x;
  constexpr int TXT = W / 8;
  const int bx0 = (bxi % TXT) * 8;
  const int gy0 = (bxi / TXT) * 16;

  const int w = tid >> 6, lane = tid & 63;
  const int j = w & 1, R0 = (w >> 1) * 8;
  const int q = lane >> 4, col = lane & 15;
  const int my = (lane >> 3) & 1, mx = lane & 7;

  if (MODE == 2 && tid < 32) sgap[tid] = 0.f;

  auto stageH = [&](int pl) {
    const u16* hsrc = hin + (size_t)pl * hPL;
    for (int i = tid; i < TH * TW * 4; i += 256) {
      int p = i >> 2, ch = i & 3;
      int sy = p / TW, sx = p - sy * TW;
      int gy = gy0 + sy - PAD, gx = bx0 + sx - PAD;
      int4 v; v.x = v.y = v.z = v.w = 0;
      if (gy >= 0 && gy < H && gx >= 0 && gx < W)
        v = *(const int4*)(hsrc + (((size_t)(b * H + gy) * W + gx) << 5) + ch * 8);
      *(int4*)(&sH[p * SSTR + ch * 8]) = v;
    }
  };
  auto stageS = [&](int pl) {
    const u16* asrc = src + (size_t)pl * sPL;
    if (MODE == 0) {
      for (int i = tid; i < TH * TW; i += 256) {
        int sy = i / TW, sx = i - sy * TW;
        int gy = gy0 + sy - PAD, gx = bx0 + sx - PAD;
        u16 v = 0;
        if (gy >= 0 && gy < H && gx >= 0 && gx < W)
          v = asrc[(size_t)b * aBStride + gy * W + gx];
        sA[i] = v;
      }
    } else {
      for (int i = tid; i < TH * TW * 4; i += 256) {
        int p = i >> 2, ch = i & 3;
        int sy = p / TW, sx = p - sy * TW;
        int gy = gy0 + sy - PAD, gx = bx0 + sx - PAD;
        int4 v; v.x = v.y = v.z = v.w = 0;
        if (gy >= 0 && gy < H && gx >= 0 && gx < W)
          v = *(const int4*)(asrc + (size_t)b * aBStride + (((size_t)gy * W + gx) << 5) + ch * 8);
        *(int4*)(&sA[p * SSTR + ch * 8]) = v;
      }
    }
  };

  const int wfoff = lane * 8;
  auto loadW = [&](int kt, bf16x8* dst) {
    const u16* wsrc;
    if (MODE == 0) wsrc = (kt == 0) ? wA : (wU + (kt - 1) * 4096);
    else           wsrc = (kt < KK) ? (wA + kt * 4096) : (wU + (kt - KK) * 4096);
#pragma unroll
    for (int g = 0; g < 4; g++)
      dst[g] = *(const bf16x8*)(wsrc + ((j + 2 * g) * 64) * 8 + wfoff);
  };

  f32x4 acc[4][4] = {};
  int abase[4];
#pragma unroll
  for (int mt = 0; mt < 4; mt++)
    abase[mt] = ((R0 + 2 * mt + my) * TW + mx) * SSTR + q * 8;

  for (int pass = 0; pass < 2; ++pass) {
    if (pass == 1) __syncthreads();      // pass-0 reads done before restage
    stageH(pass); stageS(pass);
    __syncthreads();

    bf16x8 bw[4], nw[4], nw2[4];
    loadW(0, bw);
    if (KT > 1) loadW(1, nw);
#pragma unroll 2
    for (int kt = 0; kt < KT; ++kt) {
      if (kt + 2 < KT) loadW(kt + 2, nw2);
      bf16x8 a[4];
      if (MODE == 0 && kt == 0) {
        // x-conv as GEMM over taps: A[m][k=tap]
#pragma unroll
        for (int mt = 0; mt < 4; mt++) {
          union { bf16x8 v; u16 e[8]; } u;
#pragma unroll
          for (int jj = 0; jj < 8; jj++) {
            int k = q * 8 + jj;
            u16 val = 0;
            if (k < KK) {
              int kh = k / KS, kw = k - kh * KS;
              val = sA[(R0 + 2 * mt + my + kh) * TW + (mx + kw)];
            }
            u.e[jj] = val;
          }
          a[mt] = u.v;
        }
      } else {
        int tap; const u16* s;
        if (MODE == 0)      { tap = kt - 1;  s = sH; }
        else if (kt < KK)   { tap = kt;      s = sA; }
        else                { tap = kt - KK; s = sH; }
        const int kh = tap / KS, kw = tap - kh * KS;
        const int aoff = (kh * TW + kw) * SSTR;
#pragma unroll
        for (int mt = 0; mt < 4; mt++)
          a[mt] = *(const bf16x8*)(s + abase[mt] + aoff);
      }
#pragma unroll
      for (int mt = 0; mt < 4; mt++)
#pragma unroll
        for (int g = 0; g < 4; g++)
          acc[mt][g] = __builtin_amdgcn_mfma_f32_16x16x32_bf16(a[mt], bw[g], acc[mt][g], 0, 0, 0);
#pragma unroll
      for (int g = 0; g < 4; g++) { bw[g] = nw[g]; nw[g] = nw2[g]; }
    }
  }

  // ---- epilogue: gates, state update, BN+pool / GAP ----
  const int fl = *dflag;
  const int f = j * 16 + col;
  const float bi  = ldf(bias, f, fl);
  const float bff = ldf(bias, 32 + f, fl);
  const float bg  = ldf(bias, 64 + f, fl);
  const float bo  = ldf(bias, 96 + f, fl);
  float sc = 0.f, sh = 0.f;
  if (MODE < 2) {
    sc = ldf(bng, f, fl) * rsqrtf(ldf(bnv, f, fl) + 1e-3f);
    sh = ldf(bnb, f, fl) - ldf(bnm, f, fl) * sc;
  }
  const int oy = q >> 1;
  const int ox = (q & 1) * 4;
  float gsum = 0.f;
#pragma unroll
  for (int mt = 0; mt < 4; mt++) {
    const int y = gy0 + R0 + 2 * mt + oy;
    const size_t base = (((size_t)(b * H + y) * W + (bx0 + ox)) << 5) + f;
    float bnp[4];
#pragma unroll
    for (int r = 0; r < 4; r++) {
      float zi = acc[mt][0][r] + bi;
      float zf = acc[mt][1][r] + bff;
      float zg = acc[mt][2][r] + bg;
      float zo = acc[mt][3][r] + bo;
      float ig = hsig(zi), fg = hsig(zf), og = hsig(zo);
      float gg = fmaxf(zg, 0.f);
      size_t idx = base + ((size_t)r << 5);
      float cold = cbuf[idx];
      float cn = fg * cold + ig * gg;
      cbuf[idx] = cn;
      float hn = og * fmaxf(cn, 0.f);
      u16 hhi = f2b(hn);
      hout[idx] = hhi;
      hout[idx + hPL] = f2b(hn - b2f(hhi));
      if (MODE < 2) bnp[r] = hn * sc + sh; else gsum += hn;
    }
    if (MODE < 2) {
      float p0 = fmaxf(bnp[0], bnp[1]);
      float p1 = fmaxf(bnp[2], bnp[3]);
      p0 = fmaxf(p0, __shfl_xor(p0, 32));
      p1 = fmaxf(p1, __shfl_xor(p1, 32));
      if (q < 2) {
        const int py = (gy0 + R0 + 2 * mt) >> 1;
        const int px = (bx0 >> 1) + (q & 1) * 2;
        size_t pb = (((size_t)(b * (H / 2) + py) * (W / 2) + px) << 5) + f;
        u16 phi = f2b(p0);
        pooled[pb] = phi;
        pooled[pb + pPL] = f2b(p0 - b2f(phi));
        u16 qhi = f2b(p1);
        pooled[pb + 32] = qhi;
        pooled[pb + 32 + pPL] = f2b(p1 - b2f(qhi));
      }
    }
  }
  if (MODE == 2) {
    atomicAdd(&sgap[f], gsum);
    __syncthreads();
    if (tid < 32) atomicAdd(&gap[b * 32 + tid], sgap[tid]);
  }
}

// ---------------------------------------------------------------------------
// Skewed fused dispatch: blocks 0..511 run L1(t), 512..639 run L2(t-1),
// 640..671 run L3(t-2). Cross-layer buffers (p1, p2) are parity
// double-buffered so producer/consumer planes are disjoint in-dispatch.
// 672 blocks (~2.6/CU) vs 32..512 before -> latency hiding via occupancy.
// ---------------------------------------------------------------------------
__global__ __launch_bounds__(256, 2)
void fused_step(int t, const u16* __restrict__ xc,
                const u16* __restrict__ W1x, const u16* __restrict__ W1u,
                u16* h1a, u16* h1b, float* c1, const void* b1, const void* g1,
                const void* be1, const void* m1, const void* v1, u16* p1,
                const u16* __restrict__ W2k, const u16* __restrict__ W2u,
                u16* h2a, u16* h2b, float* c2, const void* b2, const void* g2,
                const void* be2, const void* m2, const void* v2, u16* p2,
                const u16* __restrict__ W3k, const u16* __restrict__ W3u,
                u16* h3a, u16* h3b, float* c3, const void* b3,
                float* gap, const int* dflag)
{
  extern __shared__ char dsm[];
  const int bid = blockIdx.x;
  if (bid < 512) {
    if (t > 15) return;
    const u16* h1i = (t & 1) ? h1b : h1a; u16* h1o = (t & 1) ? h1a : h1b;
    step_body<5, 0, 64, 64>(bid & 31, bid >> 5, dsm,
        xc + (size_t)t * 4096, 65536, 1048576, W1x, W1u, h1i, 2097152, h1o, c1,
        b1, g1, be1, m1, v1, p1 + (size_t)(t & 1) * 1048576, 524288, nullptr, dflag);
  } else if (bid < 640) {
    const int tt = t - 1; if (tt < 0 || tt > 15) return;
    const int r = bid - 512;
    const u16* h2i = (tt & 1) ? h2b : h2a; u16* h2o = (tt & 1) ? h2a : h2b;
    step_body<5, 1, 32, 32>(r & 7, r >> 3, dsm,
        p1 + (size_t)(tt & 1) * 1048576, 32768, 524288, W2k, W2u, h2i, 524288, h2o, c2,
        b2, g2, be2, m2, v2, p2 + (size_t)(tt & 1) * 262144, 131072, nullptr, dflag);
  } else {
    const int tt = t - 2; if (tt < 0 || tt > 15) return;
    const int r = bid - 640;
    const u16* h3i = (tt & 1) ? h3b : h3a; u16* h3o = (tt & 1) ? h3a : h3b;
    step_body<3, 2, 16, 16>(r & 1, r >> 1, dsm,
        p2 + (size_t)(tt & 1) * 262144, 8192, 131072, W3k, W3u, h3i, 131072, h3o, c3,
        b3, nullptr, nullptr, nullptr, nullptr, nullptr, 0, gap, dflag);
  }
}

__global__ void repack_w(const void* __restrict__ src, u16* __restrict__ dst,
                         int taps, const int* __restrict__ dflag) {
  int i = blockIdx.x * 256 + threadIdx.x;
  if (i >= taps * 512) return;
  int fl = *dflag;
  int l = i & 63, nt = (i >> 6) & 7, tap = i >> 9;
  int q = l >> 4, col = l & 15;
  u16 tmp[8];
#pragma unroll
  for (int j = 0; j < 8; j++)
    tmp[j] = f2b(ldf(src, (tap * 32 + q * 8 + j) * 128 + nt * 16 + col, fl));
#pragma unroll
  for (int j = 0; j < 8; j++) dst[i * 8 + j] = tmp[j];
}
__global__ void repack_x(const void* __restrict__ src, u16* __restrict__ dst,
                         const int* __restrict__ dflag) {
  int i = blockIdx.x * 256 + threadIdx.x;
  if (i >= 512) return;
  int fl = *dflag;
  int l = i & 63, nt = (i >> 6) & 7;
  int q = l >> 4, col = l & 15;
#pragma unroll
  for (int j = 0; j < 8; j++) {
    int k = q * 8 + j;
    dst[i * 8 + j] = (k < 25) ? f2b(ldf(src, k * 128 + nt * 16 + col, fl)) : (u16)0;
  }
}

__global__ void zero_ws(int4* p, int n) {
  int i = blockIdx.x * 256 + threadIdx.x;
  if (i < n) { int4 z; z.x = z.y = z.z = z.w = 0; p[i] = z; }
}
__global__ void fillv(float* out, int n, float v) {
  int i = blockIdx.x * 256 + threadIdx.x;
  if (i < n) out[i] = v;
}

// ---- dense(32->4096) logits: one thread per (b,o); full-device ----
__global__ void logits_k(const float* __restrict__ gap, const void* __restrict__ wd,
                         const void* __restrict__ bd, float* __restrict__ lg,
                         const int* __restrict__ dflag) {
  int i = blockIdx.x * 256 + threadIdx.x;      // 65536 = 16 b x 4096 o
  int b = i >> 12, o = i & 4095;
  int fl = *dflag;
  float s = ldf(bd, o, fl);
  const float scl = 1.0f / 4096.0f;
#pragma unroll
  for (int f = 0; f < 32; f++)
    s += gap[b * 32 + f] * scl * ldf(wd, f * 4096 + o, fl);
  lg[i] = s;
}

// ---- per-batch softmax over 4096 logits ----
__global__ void softmax_k(const float* __restrict__ lg, float* __restrict__ out) {
  int b = blockIdx.x, tid = threadIdx.x;
  __shared__ float red[256];
  float v[16];
  float lmax = -1e30f;
#pragma unroll
  for (int i = 0; i < 16; i++) {
    v[i] = lg[b * 4096 + i * 256 + tid];
    lmax = fmaxf(lmax, v[i]);
  }
  red[tid] = lmax; __syncthreads();
  for (int st = 128; st > 0; st >>= 1) { if (tid < st) red[tid] = fmaxf(red[tid], red[tid + st]); __syncthreads(); }
  float M = red[0]; __syncthreads();
  float ls = 0.f;
#pragma unroll
  for (int i = 0; i < 16; i++) { v[i] = expf(v[i] - M); ls += v[i]; }
  red[tid] = ls; __syncthreads();
  for (int st = 128; st > 0; st >>= 1) { if (tid < st) red[tid] += red[tid + st]; __syncthreads(); }
  float inv = 1.0f / red[0];
#pragma unroll
  for (int i = 0; i < 16; i++) out[b * 4096 + i * 256 + tid] = v[i] * inv;
}

extern "C" void kernel_launch(void* const* d_in, const int* in_sizes, int n_in,
                              void* d_out, int out_size, void* d_ws, size_t ws_size,
                              hipStream_t stream)
{
  const void* x   = d_in[0];
  const void* k1  = d_in[1];
  const void* u1  = d_in[2];
  const void* b1  = d_in[3];
  const void* g1  = d_in[4];
  const void* be1 = d_in[5];
  const void* m1  = d_in[6];
  const void* v1  = d_in[7];
  const void* k2  = d_in[8];
  const void* u2  = d_in[9];
  const void* b2  = d_in[10];
  const void* g2  = d_in[11];
  const void* be2 = d_in[12];
  const void* m2  = d_in[13];
  const void* v2  = d_in[14];
  const void* k3  = d_in[15];
  const void* u3  = d_in[16];
  const void* b3  = d_in[17];
  const void* wd  = d_in[18];
  const void* bd  = d_in[19];
  float* out = (float*)d_out;   // reference output dtype is float32

  char* ws = (char*)d_ws;
  size_t off = 0;
  auto alloc = [&](size_t bytes) -> char* {
    char* p = ws + off; off = (off + bytes + 255) & ~(size_t)255; return p;
  };
  // activation u16 buffers carry 2 planes (hi, lo); p1/p2 also 2 parities
  float* c1  = (float*)alloc(2097152 * 4);
  float* c2  = (float*)alloc(524288 * 4);
  float* c3  = (float*)alloc(131072 * 4);
  u16*   h1a = (u16*)alloc(2097152 * 2 * 2);
  u16*   h2a = (u16*)alloc(524288 * 2 * 2);
  u16*   h3a = (u16*)alloc(131072 * 2 * 2);
  float* gap = (float*)alloc(512 * 4);
  int*   dflag = (int*)alloc(64);
  size_t zero_bytes = off;               // everything above starts at 0
  u16* h1b = (u16*)alloc(2097152 * 2 * 2);
  u16* h2b = (u16*)alloc(524288 * 2 * 2);
  u16* h3b = (u16*)alloc(131072 * 2 * 2);
  u16* p1  = (u16*)alloc(524288 * 2 * 2 * 2);   // 2 parities x 2 planes
  u16* p2  = (u16*)alloc(131072 * 2 * 2 * 2);
  u16* xc  = (u16*)alloc(1048576 * 2 * 2);
  float* lgbuf = (float*)alloc(65536 * 4);
  u16* W1x = (u16*)alloc(4096 * 2);
  u16* W1u = (u16*)alloc(102400 * 2);
  u16* W2k = (u16*)alloc(102400 * 2);
  u16* W2u = (u16*)alloc(102400 * 2);
  u16* W3k = (u16*)alloc(36864 * 2);
  u16* W3u = (u16*)alloc(36864 * 2);

  if (ws_size < off) {
    fillv<<<dim3((out_size + 255) / 256), 256, 0, stream>>>(out, out_size, 0.5f);
    return;
  }

  int nz = (int)(zero_bytes / 16);
  zero_ws<<<dim3((nz + 255) / 256), 256, 0, stream>>>((int4*)ws, nz);
  detect_dtype<<<1, 256, 0, stream>>>(x, dflag);
  canon_x<<<4096, 256, 0, stream>>>(x, xc, dflag, 1048576);
  repack_x<<<2, 256, 0, stream>>>(k1, W1x, dflag);
  repack_w<<<50, 256, 0, stream>>>(u1, W1u, 25, dflag);
  repack_w<<<50, 256, 0, stream>>>(k2, W2k, 25, dflag);
  repack_w<<<50, 256, 0, stream>>>(u2, W2u, 25, dflag);
  repack_w<<<18, 256, 0, stream>>>(k3, W3k, 9, dflag);
  repack_w<<<18, 256, 0, stream>>>(u3, W3u, 9, dflag);

  const size_t dyn = 38528;   // max LDS carve (MODE1) incl. sgap
  for (int t = 0; t < 18; ++t) {
    fused_step<<<672, 256, dyn, stream>>>(t, xc,
        W1x, W1u, h1a, h1b, c1, b1, g1, be1, m1, v1, p1,
        W2k, W2u, h2a, h2b, c2, b2, g2, be2, m2, v2, p2,
        W3k, W3u, h3a, h3b, c3, b3, gap, dflag);
  }
  logits_k<<<256, 256, 0, stream>>>(gap, wd, bd, lgbuf, dflag);
  softmax_k<<<16, 256, 0, stream>>>(lgbuf, out);
}

// Round 11
// 1255.806 us; speedup vs baseline: 2.5414x; 1.0764x over previous
//
#include <hip/hip_runtime.h>

typedef unsigned short u16;
typedef unsigned int u32;
typedef __attribute__((ext_vector_type(8))) short bf16x8;
typedef __attribute__((ext_vector_type(4))) float f32x4;

__device__ __forceinline__ float b2f(u16 h) {
  union { float f; unsigned u; } v; v.u = ((unsigned)h) << 16; return v.f;
}
__device__ __forceinline__ u16 f2b(float f) {
  union { float f; unsigned u; } v; v.f = f;
  unsigned r = v.u + 0x7fffu + ((v.u >> 16) & 1u);
  return (u16)(r >> 16);
}
__device__ __forceinline__ float hsig(float z) {
  return fminf(fmaxf(z * 0.16666667f + 0.5f, 0.f), 1.f);
}
__device__ __forceinline__ float ldf(const void* p, int i, int flag) {
  return flag ? b2f(((const u16*)p)[i]) : ((const float*)p)[i];
}

__global__ void detect_dtype(const void* x, int* dflag) {
  __shared__ int cnt;
  if (threadIdx.x == 0) cnt = 0;
  __syncthreads();
  const u32* w = (const u32*)x;
  int c = 0;
  for (int i = threadIdx.x; i < 512; i += 256) {
    u32 e = (w[i] >> 7) & 0xFFu;
    if (e >= 100 && e < 130) c++;
  }
  atomicAdd(&cnt, c);
  __syncthreads();
  if (threadIdx.x == 0) *dflag = (cnt >= 256) ? 1 : 0;
}

__global__ void canon_x(const void* src, u16* dst, const int* dflag, int n) {
  int i = blockIdx.x * 256 + threadIdx.x;
  if (i >= n) return;
  int fl = *dflag;
  float v = ldf(src, i, fl);
  u16 hi = f2b(v);
  dst[i] = hi;
  dst[i + n] = f2b(v - b2f(hi));
}

// ---------------------------------------------------------------------------
// ConvLSTM step body. Implicit-GEMM MFMA 16x16x32 bf16; hi/lo bf16 pairs.
// MODE0 (L1): SINGLE-PASS — hi & lo co-staged in LDS, one barrier-free
//   26-iter loop, weights loaded once per tap (serves hi+lo: 32 MFMA/iter).
// MODE1/2: 2-pass (restage lo) — L2's 4-buffer variant exceeds the 64 KB
//   dynamic-LDS cap. Depth-2 weight prefetch.
// ---------------------------------------------------------------------------
template<int KS, int MODE, int H, int W>
__device__ __forceinline__
void step_body(int bxi, int b, char* dsm,
               const u16* __restrict__ src, int aBStride, size_t sPL,
               const u16* __restrict__ wA, const u16* __restrict__ wU,
               const u16* __restrict__ hin, size_t hPL, u16* __restrict__ hout,
               float* __restrict__ cbuf, const void* __restrict__ bias,
               const void* __restrict__ bng, const void* __restrict__ bnb,
               const void* __restrict__ bnm, const void* __restrict__ bnv,
               u16* __restrict__ pooled, size_t pPL, float* __restrict__ gap,
               const int* __restrict__ dflag)
{
  constexpr int PAD = KS / 2;
  constexpr int TW = 8 + 2 * PAD;
  constexpr int TH = 16 + 2 * PAD;
  constexpr int KK = KS * KS;
  constexpr int KT = (MODE == 0) ? (KK + 1) : (2 * KK);
  constexpr int SSTR = 40;
  constexpr int HSZ = TH * TW * SSTR;
  constexpr int ASZ0 = (TH * TW + 15) & ~15;

  u16* sH0 = (u16*)dsm;                                  // h hi
  u16* sH1 = (MODE == 0) ? (sH0 + HSZ) : sH0;            // h lo (MODE0 only)
  u16* sA0 = sH0 + ((MODE == 0) ? 2 * HSZ : HSZ);        // input hi
  u16* sA1 = (MODE == 0) ? (sA0 + ASZ0) : sA0;           // input lo (MODE0)
  float* sgap = (float*)(sA0 + ((MODE == 0) ? 2 * ASZ0 : HSZ));

  const int tid = threadIdx.x;
  constexpr int TXT = W / 8;
  const int bx0 = (bxi % TXT) * 8;
  const int gy0 = (bxi / TXT) * 16;

  const int w = tid >> 6, lane = tid & 63;
  const int j = w & 1, R0 = (w >> 1) * 8;
  const int q = lane >> 4, col = lane & 15;
  const int my = (lane >> 3) & 1, mx = lane & 7;

  if (MODE == 2 && tid < 32) sgap[tid] = 0.f;

  auto stageH = [&](int pl, u16* dst) {
    const u16* hsrc = hin + (size_t)pl * hPL;
    for (int i = tid; i < TH * TW * 4; i += 256) {
      int p = i >> 2, ch = i & 3;
      int sy = p / TW, sx = p - sy * TW;
      int gy = gy0 + sy - PAD, gx = bx0 + sx - PAD;
      int4 v; v.x = v.y = v.z = v.w = 0;
      if (gy >= 0 && gy < H && gx >= 0 && gx < W)
        v = *(const int4*)(hsrc + (((size_t)(b * H + gy) * W + gx) << 5) + ch * 8);
      *(int4*)(&dst[p * SSTR + ch * 8]) = v;
    }
  };
  auto stageS = [&](int pl, u16* dst) {
    const u16* asrc = src + (size_t)pl * sPL;
    if (MODE == 0) {
      for (int i = tid; i < TH * TW; i += 256) {
        int sy = i / TW, sx = i - sy * TW;
        int gy = gy0 + sy - PAD, gx = bx0 + sx - PAD;
        u16 v = 0;
        if (gy >= 0 && gy < H && gx >= 0 && gx < W)
          v = asrc[(size_t)b * aBStride + gy * W + gx];
        dst[i] = v;
      }
    } else {
      for (int i = tid; i < TH * TW * 4; i += 256) {
        int p = i >> 2, ch = i & 3;
        int sy = p / TW, sx = p - sy * TW;
        int gy = gy0 + sy - PAD, gx = bx0 + sx - PAD;
        int4 v; v.x = v.y = v.z = v.w = 0;
        if (gy >= 0 && gy < H && gx >= 0 && gx < W)
          v = *(const int4*)(asrc + (size_t)b * aBStride + (((size_t)gy * W + gx) << 5) + ch * 8);
        *(int4*)(&dst[p * SSTR + ch * 8]) = v;
      }
    }
  };

  const int wfoff = lane * 8;
  auto loadW = [&](int kt, bf16x8* dst) {
    const u16* wsrc;
    if (MODE == 0) wsrc = (kt == 0) ? wA : (wU + (kt - 1) * 4096);
    else           wsrc = (kt < KK) ? (wA + kt * 4096) : (wU + (kt - KK) * 4096);
#pragma unroll
    for (int g = 0; g < 4; g++)
      dst[g] = *(const bf16x8*)(wsrc + ((j + 2 * g) * 64) * 8 + wfoff);
  };

  f32x4 acc[4][4] = {};
  int abase[4];
#pragma unroll
  for (int mt = 0; mt < 4; mt++)
    abase[mt] = ((R0 + 2 * mt + my) * TW + mx) * SSTR + q * 8;

  if (MODE == 0) {
    // ---- single pass: hi & lo co-staged; 1 barrier; weight loaded once/tap
    stageH(0, sH0); stageH(1, sH1); stageS(0, sA0); stageS(1, sA1);
    __syncthreads();

    bf16x8 bw[4];
    loadW(0, bw);
#pragma unroll 2
    for (int kt = 0; kt < KT; ++kt) {
      bf16x8 nxt[4];
      if (kt + 1 < KT) loadW(kt + 1, nxt);
      bf16x8 ah[4], al[4];
      if (kt == 0) {
        // x-conv as GEMM over taps: A[m][k=tap], hi and lo planes
#pragma unroll
        for (int mt = 0; mt < 4; mt++) {
          union { bf16x8 v; u16 e[8]; } uh, ul;
#pragma unroll
          for (int jj = 0; jj < 8; jj++) {
            int k = q * 8 + jj;
            u16 vh = 0, vl = 0;
            if (k < KK) {
              int kh = k / KS, kw = k - kh * KS;
              int o = (R0 + 2 * mt + my + kh) * TW + (mx + kw);
              vh = sA0[o]; vl = sA1[o];
            }
            uh.e[jj] = vh; ul.e[jj] = vl;
          }
          ah[mt] = uh.v; al[mt] = ul.v;
        }
      } else {
        const int tap = kt - 1;
        const int kh = tap / KS, kw = tap - kh * KS;
        const int aoff = (kh * TW + kw) * SSTR;
#pragma unroll
        for (int mt = 0; mt < 4; mt++) {
          ah[mt] = *(const bf16x8*)(sH0 + abase[mt] + aoff);
          al[mt] = *(const bf16x8*)(sH1 + abase[mt] + aoff);
        }
      }
#pragma unroll
      for (int mt = 0; mt < 4; mt++)
#pragma unroll
        for (int g = 0; g < 4; g++)
          acc[mt][g] = __builtin_amdgcn_mfma_f32_16x16x32_bf16(ah[mt], bw[g], acc[mt][g], 0, 0, 0);
#pragma unroll
      for (int mt = 0; mt < 4; mt++)
#pragma unroll
        for (int g = 0; g < 4; g++)
          acc[mt][g] = __builtin_amdgcn_mfma_f32_16x16x32_bf16(al[mt], bw[g], acc[mt][g], 0, 0, 0);
#pragma unroll
      for (int g = 0; g < 4; g++) bw[g] = nxt[g];
    }
  } else {
    // ---- 2-pass (hi, then restage lo); barrier-free inner loop
    for (int pass = 0; pass < 2; ++pass) {
      if (pass == 1) __syncthreads();
      stageH(pass, sH0); stageS(pass, sA0);
      __syncthreads();

      bf16x8 bw[4], nw[4], nw2[4];
      loadW(0, bw);
      if (KT > 1) loadW(1, nw);
#pragma unroll 2
      for (int kt = 0; kt < KT; ++kt) {
        if (kt + 2 < KT) loadW(kt + 2, nw2);
        int tap; const u16* s;
        if (kt < KK) { tap = kt;      s = sA0; }
        else         { tap = kt - KK; s = sH0; }
        const int kh = tap / KS, kw = tap - kh * KS;
        const int aoff = (kh * TW + kw) * SSTR;
        bf16x8 a[4];
#pragma unroll
        for (int mt = 0; mt < 4; mt++)
          a[mt] = *(const bf16x8*)(s + abase[mt] + aoff);
#pragma unroll
        for (int mt = 0; mt < 4; mt++)
#pragma unroll
          for (int g = 0; g < 4; g++)
            acc[mt][g] = __builtin_amdgcn_mfma_f32_16x16x32_bf16(a[mt], bw[g], acc[mt][g], 0, 0, 0);
#pragma unroll
        for (int g = 0; g < 4; g++) { bw[g] = nw[g]; nw[g] = nw2[g]; }
      }
    }
  }

  // ---- epilogue: gates, state update, BN+pool / GAP ----
  const int fl = *dflag;
  const int f = j * 16 + col;
  const float bi  = ldf(bias, f, fl);
  const float bff = ldf(bias, 32 + f, fl);
  const float bg  = ldf(bias, 64 + f, fl);
  const float bo  = ldf(bias, 96 + f, fl);
  float sc = 0.f, sh = 0.f;
  if (MODE < 2) {
    sc = ldf(bng, f, fl) * rsqrtf(ldf(bnv, f, fl) + 1e-3f);
    sh = ldf(bnb, f, fl) - ldf(bnm, f, fl) * sc;
  }
  const int oy = q >> 1;
  const int ox = (q & 1) * 4;
  float gsum = 0.f;
#pragma unroll
  for (int mt = 0; mt < 4; mt++) {
    const int y = gy0 + R0 + 2 * mt + oy;
    const size_t base = (((size_t)(b * H + y) * W + (bx0 + ox)) << 5) + f;
    float bnp[4];
#pragma unroll
    for (int r = 0; r < 4; r++) {
      float zi = acc[mt][0][r] + bi;
      float zf = acc[mt][1][r] + bff;
      float zg = acc[mt][2][r] + bg;
      float zo = acc[mt][3][r] + bo;
      float ig = hsig(zi), fg = hsig(zf), og = hsig(zo);
      float gg = fmaxf(zg, 0.f);
      size_t idx = base + ((size_t)r << 5);
      float cold = cbuf[idx];
      float cn = fg * cold + ig * gg;
      cbuf[idx] = cn;
      float hn = og * fmaxf(cn, 0.f);
      u16 hhi = f2b(hn);
      hout[idx] = hhi;
      hout[idx + hPL] = f2b(hn - b2f(hhi));
      if (MODE < 2) bnp[r] = hn * sc + sh; else gsum += hn;
    }
    if (MODE < 2) {
      float p0 = fmaxf(bnp[0], bnp[1]);
      float p1 = fmaxf(bnp[2], bnp[3]);
      p0 = fmaxf(p0, __shfl_xor(p0, 32));
      p1 = fmaxf(p1, __shfl_xor(p1, 32));
      if (q < 2) {
        const int py = (gy0 + R0 + 2 * mt) >> 1;
        const int px = (bx0 >> 1) + (q & 1) * 2;
        size_t pb = (((size_t)(b * (H / 2) + py) * (W / 2) + px) << 5) + f;
        u16 phi = f2b(p0);
        pooled[pb] = phi;
        pooled[pb + pPL] = f2b(p0 - b2f(phi));
        u16 qhi = f2b(p1);
        pooled[pb + 32] = qhi;
        pooled[pb + 32 + pPL] = f2b(p1 - b2f(qhi));
      }
    }
  }
  if (MODE == 2) {
    atomicAdd(&sgap[f], gsum);
    __syncthreads();
    if (tid < 32) atomicAdd(&gap[b * 32 + tid], sgap[tid]);
  }
}

// ---------------------------------------------------------------------------
// Skewed fused dispatch: blocks 0..511 run L1(t), 512..639 run L2(t-1),
// 640..671 run L3(t-2). p1/p2 parity double-buffered.
// ---------------------------------------------------------------------------
__global__ __launch_bounds__(256, 2)
void fused_step(int t, const u16* __restrict__ xc,
                const u16* __restrict__ W1x, const u16* __restrict__ W1u,
                u16* h1a, u16* h1b, float* c1, const void* b1, const void* g1,
                const void* be1, const void* m1, const void* v1, u16* p1,
                const u16* __restrict__ W2k, const u16* __restrict__ W2u,
                u16* h2a, u16* h2b, float* c2, const void* b2, const void* g2,
                const void* be2, const void* m2, const void* v2, u16* p2,
                const u16* __restrict__ W3k, const u16* __restrict__ W3u,
                u16* h3a, u16* h3b, float* c3, const void* b3,
                float* gap, const int* dflag)
{
  extern __shared__ char dsm[];
  const int bid = blockIdx.x;
  if (bid < 512) {
    if (t > 15) return;
    const u16* h1i = (t & 1) ? h1b : h1a; u16* h1o = (t & 1) ? h1a : h1b;
    step_body<5, 0, 64, 64>(bid & 31, bid >> 5, dsm,
        xc + (size_t)t * 4096, 65536, 1048576, W1x, W1u, h1i, 2097152, h1o, c1,
        b1, g1, be1, m1, v1, p1 + (size_t)(t & 1) * 1048576, 524288, nullptr, dflag);
  } else if (bid < 640) {
    const int tt = t - 1; if (tt < 0 || tt > 15) return;
    const int r = bid - 512;
    const u16* h2i = (tt & 1) ? h2b : h2a; u16* h2o = (tt & 1) ? h2a : h2b;
    step_body<5, 1, 32, 32>(r & 7, r >> 3, dsm,
        p1 + (size_t)(tt & 1) * 1048576, 32768, 524288, W2k, W2u, h2i, 524288, h2o, c2,
        b2, g2, be2, m2, v2, p2 + (size_t)(tt & 1) * 262144, 131072, nullptr, dflag);
  } else {
    const int tt = t - 2; if (tt < 0 || tt > 15) return;
    const int r = bid - 640;
    const u16* h3i = (tt & 1) ? h3b : h3a; u16* h3o = (tt & 1) ? h3a : h3b;
    step_body<3, 2, 16, 16>(r & 1, r >> 1, dsm,
        p2 + (size_t)(tt & 1) * 262144, 8192, 131072, W3k, W3u, h3i, 131072, h3o, c3,
        b3, nullptr, nullptr, nullptr, nullptr, nullptr, 0, gap, dflag);
  }
}

__global__ void repack_w(const void* __restrict__ src, u16* __restrict__ dst,
                         int taps, const int* __restrict__ dflag) {
  int i = blockIdx.x * 256 + threadIdx.x;
  if (i >= taps * 512) return;
  int fl = *dflag;
  int l = i & 63, nt = (i >> 6) & 7, tap = i >> 9;
  int q = l >> 4, col = l & 15;
  u16 tmp[8];
#pragma unroll
  for (int j = 0; j < 8; j++)
    tmp[j] = f2b(ldf(src, (tap * 32 + q * 8 + j) * 128 + nt * 16 + col, fl));
#pragma unroll
  for (int j = 0; j < 8; j++) dst[i * 8 + j] = tmp[j];
}
__global__ void repack_x(const void* __restrict__ src, u16* __restrict__ dst,
                         const int* __restrict__ dflag) {
  int i = blockIdx.x * 256 + threadIdx.x;
  if (i >= 512) return;
  int fl = *dflag;
  int l = i & 63, nt = (i >> 6) & 7;
  int q = l >> 4, col = l & 15;
#pragma unroll
  for (int j = 0; j < 8; j++) {
    int k = q * 8 + j;
    dst[i * 8 + j] = (k < 25) ? f2b(ldf(src, k * 128 + nt * 16 + col, fl)) : (u16)0;
  }
}

__global__ void zero_ws(int4* p, int n) {
  int i = blockIdx.x * 256 + threadIdx.x;
  if (i < n) { int4 z; z.x = z.y = z.z = z.w = 0; p[i] = z; }
}
__global__ void fillv(float* out, int n, float v) {
  int i = blockIdx.x * 256 + threadIdx.x;
  if (i < n) out[i] = v;
}

// ---- dense(32->4096) logits: one thread per (b,o); full-device ----
__global__ void logits_k(const float* __restrict__ gap, const void* __restrict__ wd,
                         const void* __restrict__ bd, float* __restrict__ lg,
                         const int* __restrict__ dflag) {
  int i = blockIdx.x * 256 + threadIdx.x;      // 65536 = 16 b x 4096 o
  int b = i >> 12, o = i & 4095;
  int fl = *dflag;
  float s = ldf(bd, o, fl);
  const float scl = 1.0f / 4096.0f;
#pragma unroll
  for (int f = 0; f < 32; f++)
    s += gap[b * 32 + f] * scl * ldf(wd, f * 4096 + o, fl);
  lg[i] = s;
}

// ---- per-batch softmax over 4096 logits ----
__global__ void softmax_k(const float* __restrict__ lg, float* __restrict__ out) {
  int b = blockIdx.x, tid = threadIdx.x;
  __shared__ float red[256];
  float v[16];
  float lmax = -1e30f;
#pragma unroll
  for (int i = 0; i < 16; i++) {
    v[i] = lg[b * 4096 + i * 256 + tid];
    lmax = fmaxf(lmax, v[i]);
  }
  red[tid] = lmax; __syncthreads();
  for (int st = 128; st > 0; st >>= 1) { if (tid < st) red[tid] = fmaxf(red[tid], red[tid + st]); __syncthreads(); }
  float M = red[0]; __syncthreads();
  float ls = 0.f;
#pragma unroll
  for (int i = 0; i < 16; i++) { v[i] = expf(v[i] - M); ls += v[i]; }
  red[tid] = ls; __syncthreads();
  for (int st = 128; st > 0; st >>= 1) { if (tid < st) red[tid] += red[tid + st]; __syncthreads(); }
  float inv = 1.0f / red[0];
#pragma unroll
  for (int i = 0; i < 16; i++) out[b * 4096 + i * 256 + tid] = v[i] * inv;
}

extern "C" void kernel_launch(void* const* d_in, const int* in_sizes, int n_in,
                              void* d_out, int out_size, void* d_ws, size_t ws_size,
                              hipStream_t stream)
{
  const void* x   = d_in[0];
  const void* k1  = d_in[1];
  const void* u1  = d_in[2];
  const void* b1  = d_in[3];
  const void* g1  = d_in[4];
  const void* be1 = d_in[5];
  const void* m1  = d_in[6];
  const void* v1  = d_in[7];
  const void* k2  = d_in[8];
  const void* u2  = d_in[9];
  const void* b2  = d_in[10];
  const void* g2  = d_in[11];
  const void* be2 = d_in[12];
  const void* m2  = d_in[13];
  const void* v2  = d_in[14];
  const void* k3  = d_in[15];
  const void* u3  = d_in[16];
  const void* b3  = d_in[17];
  const void* wd  = d_in[18];
  const void* bd  = d_in[19];
  float* out = (float*)d_out;   // reference output dtype is float32

  char* ws = (char*)d_ws;
  size_t off = 0;
  auto alloc = [&](size_t bytes) -> char* {
    char* p = ws + off; off = (off + bytes + 255) & ~(size_t)255; return p;
  };
  // activation u16 buffers carry 2 planes (hi, lo); p1/p2 also 2 parities
  float* c1  = (float*)alloc(2097152 * 4);
  float* c2  = (float*)alloc(524288 * 4);
  float* c3  = (float*)alloc(131072 * 4);
  u16*   h1a = (u16*)alloc(2097152 * 2 * 2);
  u16*   h2a = (u16*)alloc(524288 * 2 * 2);
  u16*   h3a = (u16*)alloc(131072 * 2 * 2);
  float* gap = (float*)alloc(512 * 4);
  int*   dflag = (int*)alloc(64);
  size_t zero_bytes = off;               // everything above starts at 0
  u16* h1b = (u16*)alloc(2097152 * 2 * 2);
  u16* h2b = (u16*)alloc(524288 * 2 * 2);
  u16* h3b = (u16*)alloc(131072 * 2 * 2);
  u16* p1  = (u16*)alloc(524288 * 2 * 2 * 2);   // 2 parities x 2 planes
  u16* p2  = (u16*)alloc(131072 * 2 * 2 * 2);
  u16* xc  = (u16*)alloc(1048576 * 2 * 2);
  float* lgbuf = (float*)alloc(65536 * 4);
  u16* W1x = (u16*)alloc(4096 * 2);
  u16* W1u = (u16*)alloc(102400 * 2);
  u16* W2k = (u16*)alloc(102400 * 2);
  u16* W2u = (u16*)alloc(102400 * 2);
  u16* W3k = (u16*)alloc(36864 * 2);
  u16* W3u = (u16*)alloc(36864 * 2);

  if (ws_size < off) {
    fillv<<<dim3((out_size + 255) / 256), 256, 0, stream>>>(out, out_size, 0.5f);
    return;
  }

  int nz = (int)(zero_bytes / 16);
  zero_ws<<<dim3((nz + 255) / 256), 256, 0, stream>>>((int4*)ws, nz);
  detect_dtype<<<1, 256, 0, stream>>>(x, dflag);
  canon_x<<<4096, 256, 0, stream>>>(x, xc, dflag, 1048576);
  repack_x<<<2, 256, 0, stream>>>(k1, W1x, dflag);
  repack_w<<<50, 256, 0, stream>>>(u1, W1u, 25, dflag);
  repack_w<<<50, 256, 0, stream>>>(k2, W2k, 25, dflag);
  repack_w<<<50, 256, 0, stream>>>(u2, W2u, 25, dflag);
  repack_w<<<18, 256, 0, stream>>>(k3, W3k, 9, dflag);
  repack_w<<<18, 256, 0, stream>>>(u3, W3u, 9, dflag);

  // dyn LDS = max over roles: MODE0 single-pass 39424 B; MODE1 2-pass 38400;
  // MODE2 2-pass 28800 (+sgap). Keep <= 64 KB dynamic-LDS cap, 4 blocks/CU.
  const size_t dyn = 39680;
  for (int t = 0; t < 18; ++t) {
    fused_step<<<672, 256, dyn, stream>>>(t, xc,
        W1x, W1u, h1a, h1b, c1, b1, g1, be1, m1, v1, p1,
        W2k, W2u, h2a, h2b, c2, b2, g2, be2, m2, v2, p2,
        W3k, W3u, h3a, h3b, c3, b3, gap, dflag);
  }
  logits_k<<<256, 256, 0, stream>>>(gap, wd, bd, lgbuf, dflag);
  softmax_k<<<16, 256, 0, stream>>>(lgbuf, out);
}

// Round 12
// 1144.205 us; speedup vs baseline: 2.7892x; 1.0975x over previous
//
#include <hip/hip_runtime.h>

typedef unsigned short u16;
typedef unsigned int u32;
typedef __attribute__((ext_vector_type(8))) short bf16x8;
typedef __attribute__((ext_vector_type(4))) float f32x4;

__device__ __forceinline__ float b2f(u16 h) {
  union { float f; unsigned u; } v; v.u = ((unsigned)h) << 16; return v.f;
}
__device__ __forceinline__ u16 f2b(float f) {
  union { float f; unsigned u; } v; v.f = f;
  unsigned r = v.u + 0x7fffu + ((v.u >> 16) & 1u);
  return (u16)(r >> 16);
}
__device__ __forceinline__ float hsig(float z) {
  return fminf(fmaxf(z * 0.16666667f + 0.5f, 0.f), 1.f);
}
__device__ __forceinline__ float ldf(const void* p, int i, int flag) {
  return flag ? b2f(((const u16*)p)[i]) : ((const float*)p)[i];
}

__global__ void detect_dtype(const void* x, int* dflag) {
  __shared__ int cnt;
  if (threadIdx.x == 0) cnt = 0;
  __syncthreads();
  const u32* w = (const u32*)x;
  int c = 0;
  for (int i = threadIdx.x; i < 512; i += 256) {
    u32 e = (w[i] >> 7) & 0xFFu;
    if (e >= 100 && e < 130) c++;
  }
  atomicAdd(&cnt, c);
  __syncthreads();
  if (threadIdx.x == 0) *dflag = (cnt >= 256) ? 1 : 0;
}

__global__ void canon_x(const void* src, u16* dst, const int* dflag, int n) {
  int i = blockIdx.x * 256 + threadIdx.x;
  if (i >= n) return;
  int fl = *dflag;
  float v = ldf(src, i, fl);
  u16 hi = f2b(v);
  dst[i] = hi;
  dst[i + n] = f2b(v - b2f(hi));
}

// ---------------------------------------------------------------------------
// ConvLSTM step body. Implicit-GEMM MFMA 16x16x32 bf16; hi/lo bf16 pairs.
// MODE0 (L1): single-pass, hi & lo co-staged, weight loaded once per tap.
// MODE1/2: 2-pass; A-fragment SOFTWARE PIPELINE — next iteration's ds_reads
//   issued before this iteration's MFMAs, hiding the ~120-cyc LDS latency
//   under the ~78-cyc MFMA block (round-11 pole: L2's 100-iter serial loop).
// ---------------------------------------------------------------------------
template<int KS, int MODE, int H, int W>
__device__ __forceinline__
void step_body(int bxi, int b, char* dsm,
               const u16* __restrict__ src, int aBStride, size_t sPL,
               const u16* __restrict__ wA, const u16* __restrict__ wU,
               const u16* __restrict__ hin, size_t hPL, u16* __restrict__ hout,
               float* __restrict__ cbuf, const void* __restrict__ bias,
               const void* __restrict__ bng, const void* __restrict__ bnb,
               const void* __restrict__ bnm, const void* __restrict__ bnv,
               u16* __restrict__ pooled, size_t pPL, float* __restrict__ gap,
               const int* __restrict__ dflag)
{
  constexpr int PAD = KS / 2;
  constexpr int TW = 8 + 2 * PAD;
  constexpr int TH = 16 + 2 * PAD;
  constexpr int KK = KS * KS;
  constexpr int KT = (MODE == 0) ? (KK + 1) : (2 * KK);
  constexpr int SSTR = 40;
  constexpr int HSZ = TH * TW * SSTR;
  constexpr int ASZ0 = (TH * TW + 15) & ~15;

  u16* sH0 = (u16*)dsm;
  u16* sH1 = (MODE == 0) ? (sH0 + HSZ) : sH0;
  u16* sA0 = sH0 + ((MODE == 0) ? 2 * HSZ : HSZ);
  u16* sA1 = (MODE == 0) ? (sA0 + ASZ0) : sA0;
  float* sgap = (float*)(sA0 + ((MODE == 0) ? 2 * ASZ0 : HSZ));

  const int tid = threadIdx.x;
  constexpr int TXT = W / 8;
  const int bx0 = (bxi % TXT) * 8;
  const int gy0 = (bxi / TXT) * 16;

  const int w = tid >> 6, lane = tid & 63;
  const int j = w & 1, R0 = (w >> 1) * 8;
  const int q = lane >> 4, col = lane & 15;
  const int my = (lane >> 3) & 1, mx = lane & 7;

  if (MODE == 2 && tid < 32) sgap[tid] = 0.f;

  auto stageH = [&](int pl, u16* dst) {
    const u16* hsrc = hin + (size_t)pl * hPL;
    for (int i = tid; i < TH * TW * 4; i += 256) {
      int p = i >> 2, ch = i & 3;
      int sy = p / TW, sx = p - sy * TW;
      int gy = gy0 + sy - PAD, gx = bx0 + sx - PAD;
      int4 v; v.x = v.y = v.z = v.w = 0;
      if (gy >= 0 && gy < H && gx >= 0 && gx < W)
        v = *(const int4*)(hsrc + (((size_t)(b * H + gy) * W + gx) << 5) + ch * 8);
      *(int4*)(&dst[p * SSTR + ch * 8]) = v;
    }
  };
  auto stageS = [&](int pl, u16* dst) {
    const u16* asrc = src + (size_t)pl * sPL;
    if (MODE == 0) {
      for (int i = tid; i < TH * TW; i += 256) {
        int sy = i / TW, sx = i - sy * TW;
        int gy = gy0 + sy - PAD, gx = bx0 + sx - PAD;
        u16 v = 0;
        if (gy >= 0 && gy < H && gx >= 0 && gx < W)
          v = asrc[(size_t)b * aBStride + gy * W + gx];
        dst[i] = v;
      }
    } else {
      for (int i = tid; i < TH * TW * 4; i += 256) {
        int p = i >> 2, ch = i & 3;
        int sy = p / TW, sx = p - sy * TW;
        int gy = gy0 + sy - PAD, gx = bx0 + sx - PAD;
        int4 v; v.x = v.y = v.z = v.w = 0;
        if (gy >= 0 && gy < H && gx >= 0 && gx < W)
          v = *(const int4*)(asrc + (size_t)b * aBStride + (((size_t)gy * W + gx) << 5) + ch * 8);
        *(int4*)(&dst[p * SSTR + ch * 8]) = v;
      }
    }
  };

  const int wfoff = lane * 8;
  auto loadW = [&](int kt, bf16x8* dst) {
    const u16* wsrc;
    if (MODE == 0) wsrc = (kt == 0) ? wA : (wU + (kt - 1) * 4096);
    else           wsrc = (kt < KK) ? (wA + kt * 4096) : (wU + (kt - KK) * 4096);
#pragma unroll
    for (int g = 0; g < 4; g++)
      dst[g] = *(const bf16x8*)(wsrc + ((j + 2 * g) * 64) * 8 + wfoff);
  };

  f32x4 acc[4][4] = {};
  int abase[4];
#pragma unroll
  for (int mt = 0; mt < 4; mt++)
    abase[mt] = ((R0 + 2 * mt + my) * TW + mx) * SSTR + q * 8;

  if (MODE == 0) {
    stageH(0, sH0); stageH(1, sH1); stageS(0, sA0); stageS(1, sA1);
    __syncthreads();

    bf16x8 bw[4];
    loadW(0, bw);
#pragma unroll 2
    for (int kt = 0; kt < KT; ++kt) {
      bf16x8 nxt[4];
      if (kt + 1 < KT) loadW(kt + 1, nxt);
      bf16x8 ah[4], al[4];
      if (kt == 0) {
#pragma unroll
        for (int mt = 0; mt < 4; mt++) {
          union { bf16x8 v; u16 e[8]; } uh, ul;
#pragma unroll
          for (int jj = 0; jj < 8; jj++) {
            int k = q * 8 + jj;
            u16 vh = 0, vl = 0;
            if (k < KK) {
              int kh = k / KS, kw = k - kh * KS;
              int o = (R0 + 2 * mt + my + kh) * TW + (mx + kw);
              vh = sA0[o]; vl = sA1[o];
            }
            uh.e[jj] = vh; ul.e[jj] = vl;
          }
          ah[mt] = uh.v; al[mt] = ul.v;
        }
      } else {
        const int tap = kt - 1;
        const int kh = tap / KS, kw = tap - kh * KS;
        const int aoff = (kh * TW + kw) * SSTR;
#pragma unroll
        for (int mt = 0; mt < 4; mt++) {
          ah[mt] = *(const bf16x8*)(sH0 + abase[mt] + aoff);
          al[mt] = *(const bf16x8*)(sH1 + abase[mt] + aoff);
        }
      }
#pragma unroll
      for (int mt = 0; mt < 4; mt++)
#pragma unroll
        for (int g = 0; g < 4; g++)
          acc[mt][g] = __builtin_amdgcn_mfma_f32_16x16x32_bf16(ah[mt], bw[g], acc[mt][g], 0, 0, 0);
#pragma unroll
      for (int mt = 0; mt < 4; mt++)
#pragma unroll
        for (int g = 0; g < 4; g++)
          acc[mt][g] = __builtin_amdgcn_mfma_f32_16x16x32_bf16(al[mt], bw[g], acc[mt][g], 0, 0, 0);
#pragma unroll
      for (int g = 0; g < 4; g++) bw[g] = nxt[g];
    }
  } else {
    // ---- 2-pass, A-pipelined barrier-free inner loop
    auto loadA = [&](int kt, bf16x8* dst) {
      int tap; const u16* s;
      if (kt < KK) { tap = kt;      s = sA0; }
      else         { tap = kt - KK; s = sH0; }
      const int kh = tap / KS, kw = tap - kh * KS;
      const int aoff = (kh * TW + kw) * SSTR;
#pragma unroll
      for (int mt = 0; mt < 4; mt++)
        dst[mt] = *(const bf16x8*)(s + abase[mt] + aoff);
    };
    for (int pass = 0; pass < 2; ++pass) {
      if (pass == 1) __syncthreads();
      stageH(pass, sH0); stageS(pass, sA0);
      __syncthreads();

      bf16x8 bw[4], nw[4];
      loadW(0, bw);
      if (KT > 1) loadW(1, nw);
      bf16x8 a[4], an[4];
      loadA(0, a);
#pragma unroll 2
      for (int kt = 0; kt < KT; ++kt) {
        if (kt + 1 < KT) loadA(kt + 1, an);      // prefetch next A (ds)
        bf16x8 nw2[4];
        if (kt + 2 < KT) loadW(kt + 2, nw2);     // prefetch weights (global)
#pragma unroll
        for (int mt = 0; mt < 4; mt++)
#pragma unroll
          for (int g = 0; g < 4; g++)
            acc[mt][g] = __builtin_amdgcn_mfma_f32_16x16x32_bf16(a[mt], bw[g], acc[mt][g], 0, 0, 0);
#pragma unroll
        for (int mt = 0; mt < 4; mt++) a[mt] = an[mt];
#pragma unroll
        for (int g = 0; g < 4; g++) { bw[g] = nw[g]; nw[g] = nw2[g]; }
      }
    }
  }

  // ---- epilogue: gates, state update, BN+pool / GAP ----
  const int fl = *dflag;
  const int f = j * 16 + col;
  const float bi  = ldf(bias, f, fl);
  const float bff = ldf(bias, 32 + f, fl);
  const float bg  = ldf(bias, 64 + f, fl);
  const float bo  = ldf(bias, 96 + f, fl);
  float sc = 0.f, sh = 0.f;
  if (MODE < 2) {
    sc = ldf(bng, f, fl) * rsqrtf(ldf(bnv, f, fl) + 1e-3f);
    sh = ldf(bnb, f, fl) - ldf(bnm, f, fl) * sc;
  }
  const int oy = q >> 1;
  const int ox = (q & 1) * 4;
  float gsum = 0.f;
#pragma unroll
  for (int mt = 0; mt < 4; mt++) {
    const int y = gy0 + R0 + 2 * mt + oy;
    const size_t base = (((size_t)(b * H + y) * W + (bx0 + ox)) << 5) + f;
    float bnp[4];
#pragma unroll
    for (int r = 0; r < 4; r++) {
      float zi = acc[mt][0][r] + bi;
      float zf = acc[mt][1][r] + bff;
      float zg = acc[mt][2][r] + bg;
      float zo = acc[mt][3][r] + bo;
      float ig = hsig(zi), fg = hsig(zf), og = hsig(zo);
      float gg = fmaxf(zg, 0.f);
      size_t idx = base + ((size_t)r << 5);
      float cold = cbuf[idx];
      float cn = fg * cold + ig * gg;
      cbuf[idx] = cn;
      float hn = og * fmaxf(cn, 0.f);
      u16 hhi = f2b(hn);
      hout[idx] = hhi;
      hout[idx + hPL] = f2b(hn - b2f(hhi));
      if (MODE < 2) bnp[r] = hn * sc + sh; else gsum += hn;
    }
    if (MODE < 2) {
      float p0 = fmaxf(bnp[0], bnp[1]);
      float p1 = fmaxf(bnp[2], bnp[3]);
      p0 = fmaxf(p0, __shfl_xor(p0, 32));
      p1 = fmaxf(p1, __shfl_xor(p1, 32));
      if (q < 2) {
        const int py = (gy0 + R0 + 2 * mt) >> 1;
        const int px = (bx0 >> 1) + (q & 1) * 2;
        size_t pb = (((size_t)(b * (H / 2) + py) * (W / 2) + px) << 5) + f;
        u16 phi = f2b(p0);
        pooled[pb] = phi;
        pooled[pb + pPL] = f2b(p0 - b2f(phi));
        u16 qhi = f2b(p1);
        pooled[pb + 32] = qhi;
        pooled[pb + 32 + pPL] = f2b(p1 - b2f(qhi));
      }
    }
  }
  if (MODE == 2) {
    atomicAdd(&sgap[f], gsum);
    __syncthreads();
    if (tid < 32) atomicAdd(&gap[b * 32 + tid], sgap[tid]);
  }
}

// ---------------------------------------------------------------------------
// Skewed fused dispatch, ROLE-INTERLEAVED: 672 = 21 x 32 groups; within each
// group of 21 consecutive block ids: 16 L1, 4 L2, 1 L3. In-order block issue
// then starts all roles together even when capacity-limited (round-11 fix:
// blocks 0..511 all-L1 serialized the roles into phases).
// ---------------------------------------------------------------------------
__global__ __launch_bounds__(256, 2)
void fused_step(int t, const u16* __restrict__ xc,
                const u16* __restrict__ W1x, const u16* __restrict__ W1u,
                u16* h1a, u16* h1b, float* c1, const void* b1, const void* g1,
                const void* be1, const void* m1, const void* v1, u16* p1,
                const u16* __restrict__ W2k, const u16* __restrict__ W2u,
                u16* h2a, u16* h2b, float* c2, const void* b2, const void* g2,
                const void* be2, const void* m2, const void* v2, u16* p2,
                const u16* __restrict__ W3k, const u16* __restrict__ W3u,
                u16* h3a, u16* h3b, float* c3, const void* b3,
                float* gap, const int* dflag)
{
  extern __shared__ char dsm[];
  const int grp = blockIdx.x / 21;
  const int r   = blockIdx.x % 21;
  if (r < 16) {
    if (t > 15) return;
    const int idx = grp * 16 + r;            // 0..511
    const u16* h1i = (t & 1) ? h1b : h1a; u16* h1o = (t & 1) ? h1a : h1b;
    step_body<5, 0, 64, 64>(idx & 31, idx >> 5, dsm,
        xc + (size_t)t * 4096, 65536, 1048576, W1x, W1u, h1i, 2097152, h1o, c1,
        b1, g1, be1, m1, v1, p1 + (size_t)(t & 1) * 1048576, 524288, nullptr, dflag);
  } else if (r < 20) {
    const int tt = t - 1; if (tt < 0 || tt > 15) return;
    const int idx = grp * 4 + (r - 16);      // 0..127
    const u16* h2i = (tt & 1) ? h2b : h2a; u16* h2o = (tt & 1) ? h2a : h2b;
    step_body<5, 1, 32, 32>(idx & 7, idx >> 3, dsm,
        p1 + (size_t)(tt & 1) * 1048576, 32768, 524288, W2k, W2u, h2i, 524288, h2o, c2,
        b2, g2, be2, m2, v2, p2 + (size_t)(tt & 1) * 262144, 131072, nullptr, dflag);
  } else {
    const int tt = t - 2; if (tt < 0 || tt > 15) return;
    const int idx = grp;                     // 0..31
    const u16* h3i = (tt & 1) ? h3b : h3a; u16* h3o = (tt & 1) ? h3a : h3b;
    step_body<3, 2, 16, 16>(idx & 1, idx >> 1, dsm,
        p2 + (size_t)(tt & 1) * 262144, 8192, 131072, W3k, W3u, h3i, 131072, h3o, c3,
        b3, nullptr, nullptr, nullptr, nullptr, nullptr, 0, gap, dflag);
  }
}

__global__ void repack_w(const void* __restrict__ src, u16* __restrict__ dst,
                         int taps, const int* __restrict__ dflag) {
  int i = blockIdx.x * 256 + threadIdx.x;
  if (i >= taps * 512) return;
  int fl = *dflag;
  int l = i & 63, nt = (i >> 6) & 7, tap = i >> 9;
  int q = l >> 4, col = l & 15;
  u16 tmp[8];
#pragma unroll
  for (int j = 0; j < 8; j++)
    tmp[j] = f2b(ldf(src, (tap * 32 + q * 8 + j) * 128 + nt * 16 + col, fl));
#pragma unroll
  for (int j = 0; j < 8; j++) dst[i * 8 + j] = tmp[j];
}
__global__ void repack_x(const void* __restrict__ src, u16* __restrict__ dst,
                         const int* __restrict__ dflag) {
  int i = blockIdx.x * 256 + threadIdx.x;
  if (i >= 512) return;
  int fl = *dflag;
  int l = i & 63, nt = (i >> 6) & 7;
  int q = l >> 4, col = l & 15;
#pragma unroll
  for (int j = 0; j < 8; j++) {
    int k = q * 8 + j;
    dst[i * 8 + j] = (k < 25) ? f2b(ldf(src, k * 128 + nt * 16 + col, fl)) : (u16)0;
  }
}

__global__ void zero_ws(int4* p, int n) {
  int i = blockIdx.x * 256 + threadIdx.x;
  if (i < n) { int4 z; z.x = z.y = z.z = z.w = 0; p[i] = z; }
}
__global__ void fillv(float* out, int n, float v) {
  int i = blockIdx.x * 256 + threadIdx.x;
  if (i < n) out[i] = v;
}

// ---- dense(32->4096) logits: one thread per (b,o); full-device ----
__global__ void logits_k(const float* __restrict__ gap, const void* __restrict__ wd,
                         const void* __restrict__ bd, float* __restrict__ lg,
                         const int* __restrict__ dflag) {
  int i = blockIdx.x * 256 + threadIdx.x;      // 65536 = 16 b x 4096 o
  int b = i >> 12, o = i & 4095;
  int fl = *dflag;
  float s = ldf(bd, o, fl);
  const float scl = 1.0f / 4096.0f;
#pragma unroll
  for (int f = 0; f < 32; f++)
    s += gap[b * 32 + f] * scl * ldf(wd, f * 4096 + o, fl);
  lg[i] = s;
}

// ---- per-batch softmax over 4096 logits ----
__global__ void softmax_k(const float* __restrict__ lg, float* __restrict__ out) {
  int b = blockIdx.x, tid = threadIdx.x;
  __shared__ float red[256];
  float v[16];
  float lmax = -1e30f;
#pragma unroll
  for (int i = 0; i < 16; i++) {
    v[i] = lg[b * 4096 + i * 256 + tid];
    lmax = fmaxf(lmax, v[i]);
  }
  red[tid] = lmax; __syncthreads();
  for (int st = 128; st > 0; st >>= 1) { if (tid < st) red[tid] = fmaxf(red[tid], red[tid + st]); __syncthreads(); }
  float M = red[0]; __syncthreads();
  float ls = 0.f;
#pragma unroll
  for (int i = 0; i < 16; i++) { v[i] = expf(v[i] - M); ls += v[i]; }
  red[tid] = ls; __syncthreads();
  for (int st = 128; st > 0; st >>= 1) { if (tid < st) red[tid] += red[tid + st]; __syncthreads(); }
  float inv = 1.0f / red[0];
#pragma unroll
  for (int i = 0; i < 16; i++) out[b * 4096 + i * 256 + tid] = v[i] * inv;
}

extern "C" void kernel_launch(void* const* d_in, const int* in_sizes, int n_in,
                              void* d_out, int out_size, void* d_ws, size_t ws_size,
                              hipStream_t stream)
{
  const void* x   = d_in[0];
  const void* k1  = d_in[1];
  const void* u1  = d_in[2];
  const void* b1  = d_in[3];
  const void* g1  = d_in[4];
  const void* be1 = d_in[5];
  const void* m1  = d_in[6];
  const void* v1  = d_in[7];
  const void* k2  = d_in[8];
  const void* u2  = d_in[9];
  const void* b2  = d_in[10];
  const void* g2  = d_in[11];
  const void* be2 = d_in[12];
  const void* m2  = d_in[13];
  const void* v2  = d_in[14];
  const void* k3  = d_in[15];
  const void* u3  = d_in[16];
  const void* b3  = d_in[17];
  const void* wd  = d_in[18];
  const void* bd  = d_in[19];
  float* out = (float*)d_out;   // reference output dtype is float32

  char* ws = (char*)d_ws;
  size_t off = 0;
  auto alloc = [&](size_t bytes) -> char* {
    char* p = ws + off; off = (off + bytes + 255) & ~(size_t)255; return p;
  };
  // activation u16 buffers carry 2 planes (hi, lo); p1/p2 also 2 parities
  float* c1  = (float*)alloc(2097152 * 4);
  float* c2  = (float*)alloc(524288 * 4);
  float* c3  = (float*)alloc(131072 * 4);
  u16*   h1a = (u16*)alloc(2097152 * 2 * 2);
  u16*   h2a = (u16*)alloc(524288 * 2 * 2);
  u16*   h3a = (u16*)alloc(131072 * 2 * 2);
  float* gap = (float*)alloc(512 * 4);
  int*   dflag = (int*)alloc(64);
  size_t zero_bytes = off;               // everything above starts at 0
  u16* h1b = (u16*)alloc(2097152 * 2 * 2);
  u16* h2b = (u16*)alloc(524288 * 2 * 2);
  u16* h3b = (u16*)alloc(131072 * 2 * 2);
  u16* p1  = (u16*)alloc(524288 * 2 * 2 * 2);   // 2 parities x 2 planes
  u16* p2  = (u16*)alloc(131072 * 2 * 2 * 2);
  u16* xc  = (u16*)alloc(1048576 * 2 * 2);
  float* lgbuf = (float*)alloc(65536 * 4);
  u16* W1x = (u16*)alloc(4096 * 2);
  u16* W1u = (u16*)alloc(102400 * 2);
  u16* W2k = (u16*)alloc(102400 * 2);
  u16* W2u = (u16*)alloc(102400 * 2);
  u16* W3k = (u16*)alloc(36864 * 2);
  u16* W3u = (u16*)alloc(36864 * 2);

  if (ws_size < off) {
    fillv<<<dim3((out_size + 255) / 256), 256, 0, stream>>>(out, out_size, 0.5f);
    return;
  }

  int nz = (int)(zero_bytes / 16);
  zero_ws<<<dim3((nz + 255) / 256), 256, 0, stream>>>((int4*)ws, nz);
  detect_dtype<<<1, 256, 0, stream>>>(x, dflag);
  canon_x<<<4096, 256, 0, stream>>>(x, xc, dflag, 1048576);
  repack_x<<<2, 256, 0, stream>>>(k1, W1x, dflag);
  repack_w<<<50, 256, 0, stream>>>(u1, W1u, 25, dflag);
  repack_w<<<50, 256, 0, stream>>>(k2, W2k, 25, dflag);
  repack_w<<<50, 256, 0, stream>>>(u2, W2u, 25, dflag);
  repack_w<<<18, 256, 0, stream>>>(k3, W3k, 9, dflag);
  repack_w<<<18, 256, 0, stream>>>(u3, W3u, 9, dflag);

  // dyn LDS = max over roles: MODE0 single-pass 39424 B (+pad). <= 64 KB cap.
  const size_t dyn = 39680;
  for (int t = 0; t < 18; ++t) {
    fused_step<<<672, 256, dyn, stream>>>(t, xc,
        W1x, W1u, h1a, h1b, c1, b1, g1, be1, m1, v1, p1,
        W2k, W2u, h2a, h2b, c2, b2, g2, be2, m2, v2, p2,
        W3k, W3u, h3a, h3b, c3, b3, gap, dflag);
  }
  logits_k<<<256, 256, 0, stream>>>(gap, wd, bd, lgbuf, dflag);
  softmax_k<<<16, 256, 0, stream>>>(lgbuf, out);
}